// Round 4
// baseline (660.230 us; speedup 1.0000x reference)
//
#include <hip/hip_runtime.h>
#include <hip/hip_bf16.h>

#define HW 16384
#define W 128
#define C 128
#define HID 256

// ---------------- kernel 0: zero the stat accumulators ----------------
__global__ void zero_acc_kernel(float* acc) {
    acc[0] = 0.f;
    acc[1] = 0.f;
}

// ---------------- kernel 1: q/k/v 1x1 convs ----------------
// q -> q_t[pix][C]; k,v -> kv_t[pix][256] (k in [0,128), v in [128,256))
// grid 1024, block 256. 16 pixels per block.
__global__ void qkv_kernel(const float* __restrict__ q_in, const float* __restrict__ k_in,
                           const float* __restrict__ v_in,
                           const float* __restrict__ w_q, const float* __restrict__ w_k,
                           const float* __restrict__ w_v,
                           float* __restrict__ q_t, float* __restrict__ kv_t) {
    __shared__ float xs[3][C * 16];
    const int p0 = blockIdx.x * 16;
    const int t = threadIdx.x;

    #pragma unroll
    for (int it = 0; it < 8; ++it) {
        int e = t + 256 * it;          // e = c*16 + j
        int c = e >> 4, j = e & 15;
        xs[0][e] = q_in[c * HW + p0 + j];
        xs[1][e] = k_in[c * HW + p0 + j];
        xs[2][e] = v_in[c * HW + p0 + j];
    }
    __syncthreads();

    const int o = t & 127, half = t >> 7;
    const float* Ws[3] = {w_q, w_k, w_v};

    #pragma unroll
    for (int m = 0; m < 3; ++m) {
        float acc[8] = {0.f, 0.f, 0.f, 0.f, 0.f, 0.f, 0.f, 0.f};
        const float* Wr = Ws[m] + o * C;
        const float* xb = &xs[m][half * 8];
        for (int c = 0; c < C; ++c) {
            float w = Wr[c];
            const float* xr = xb + c * 16;
            #pragma unroll
            for (int i = 0; i < 8; ++i) acc[i] += w * xr[i];
        }
        #pragma unroll
        for (int i = 0; i < 8; ++i) {
            int p = p0 + half * 8 + i;
            if (m == 0)      q_t[p * C + o] = acc[i];
            else if (m == 1) kv_t[p * 256 + o] = acc[i];
            else             kv_t[p * 256 + 128 + o] = acc[i];
        }
    }
}

// ---------------- kernel 2: deformable sampling + attention (online softmax) ----------------
// 1024 blocks x 256 threads, grid-stride over 2048 jobs (job = 8 consecutive-x
// pixels, 32 threads/pixel, 4 ch/thread, float4 gathers). Two passes: resident
// job window is a contiguous pixel band -> sliding L2 working set, mapping-agnostic.
__global__ void attn_kernel(const float* __restrict__ q_t, const float* __restrict__ kv_t,
                            const float* __restrict__ deform, float* __restrict__ ao_t) {
    __shared__ int   s_off[8][25][4];
    __shared__ float s_w[8][25][4];

    const int t = threadIdx.x;
    const int pi = t >> 5;     // pixel within job
    const int g = t & 31;      // channel group (4 channels each)
    const char* kvb = (const char*)kv_t;
    const int go = g * 16;

    for (int pass = 0; pass < 2; ++pass) {
        const int jj = blockIdx.x + pass * 1024;
        const int y = jj >> 4;
        const int x = ((jj & 15) << 3) + pi;
        const int pix = y * W + x;

        if (pass) __syncthreads();    // protect LDS reuse across jobs

        if (g < 25) {
            float dx = deform[pix];
            float dy = deform[HW + pix];
            int iy = g / 5, ix = g - iy * 5;
            float vx = (float)x + (float)(ix - 2) + dx;
            float vy = (float)y + (float)(iy - 2) + dy;
            float x0f = floorf(vx), y0f = floorf(vy);
            float fx = vx - x0f, fy = vy - y0f;
            float wx[2] = {1.f - fx, fx};
            float wy[2] = {1.f - fy, fy};
            #pragma unroll
            for (int cy = 0; cy < 2; ++cy) {
                #pragma unroll
                for (int cx = 0; cx < 2; ++cx) {
                    float xf = x0f + (float)cx;
                    float yf = y0f + (float)cy;
                    bool valid = (xf >= 0.f) & (xf <= 127.f) & (yf >= 0.f) & (yf <= 127.f);
                    int xi = min(max((int)xf, 0), 127);
                    int yi = min(max((int)yf, 0), 127);
                    s_off[pi][g][cy * 2 + cx] = (yi * W + xi) * 1024;   // byte offset of kv row
                    s_w[pi][g][cy * 2 + cx] = valid ? wx[cx] * wy[cy] : 0.f;
                }
            }
        }
        __syncthreads();

        float4 q4 = *(const float4*)(q_t + (size_t)pix * C + 4 * g);
        q4.x *= 0.25f; q4.y *= 0.25f; q4.z *= 0.25f; q4.w *= 0.25f;   // 1/sqrt(16)

        float m = -1e30f;
        float sum = 0.f;
        float4 oc = {0.f, 0.f, 0.f, 0.f};

        #pragma unroll
        for (int p = 0; p < 25; ++p) {
            int4   off = *(const int4*)&s_off[pi][p][0];
            float4 w   = *(const float4*)&s_w[pi][p][0];
            float4 k0 = *(const float4*)(kvb + off.x + go);
            float4 k1 = *(const float4*)(kvb + off.y + go);
            float4 k2 = *(const float4*)(kvb + off.z + go);
            float4 k3 = *(const float4*)(kvb + off.w + go);
            float4 v0 = *(const float4*)(kvb + off.x + 512 + go);
            float4 v1 = *(const float4*)(kvb + off.y + 512 + go);
            float4 v2 = *(const float4*)(kvb + off.z + 512 + go);
            float4 v3 = *(const float4*)(kvb + off.w + 512 + go);

            float4 ks;
            ks.x = w.x * k0.x + w.y * k1.x + w.z * k2.x + w.w * k3.x;
            ks.y = w.x * k0.y + w.y * k1.y + w.z * k2.y + w.w * k3.y;
            ks.z = w.x * k0.z + w.y * k1.z + w.z * k2.z + w.w * k3.z;
            ks.w = w.x * k0.w + w.y * k1.w + w.z * k2.w + w.w * k3.w;
            float sp = q4.x * ks.x + q4.y * ks.y + q4.z * ks.z + q4.w * ks.w;
            sp += __shfl_xor(sp, 1);
            sp += __shfl_xor(sp, 2);    // 4-thread group = one head (16 channels)

            float4 vs;
            vs.x = w.x * v0.x + w.y * v1.x + w.z * v2.x + w.w * v3.x;
            vs.y = w.x * v0.y + w.y * v1.y + w.z * v2.y + w.w * v3.y;
            vs.z = w.x * v0.z + w.y * v1.z + w.z * v2.z + w.w * v3.z;
            vs.w = w.x * v0.w + w.y * v1.w + w.z * v2.w + w.w * v3.w;

            float mn   = fmaxf(m, sp);
            float corr = __expf(m - mn);
            float e    = __expf(sp - mn);
            sum  = sum * corr + e;
            oc.x = oc.x * corr + e * vs.x;
            oc.y = oc.y * corr + e * vs.y;
            oc.z = oc.z * corr + e * vs.z;
            oc.w = oc.w * corr + e * vs.w;
            m = mn;
        }

        float inv = 1.f / sum;
        oc.x *= inv; oc.y *= inv; oc.z *= inv; oc.w *= inv;
        *(float4*)(ao_t + (size_t)pix * C + 4 * g) = oc;
    }
}

// ---------------- kernel 3: fc + MLP + residual + stats ----------------
// grid 1024, block 256. 16 pixels per block. out2 goes straight into d_out [C][HW].
__global__ void mlp_kernel(const float* __restrict__ ao_t, const float* __restrict__ w_fc,
                           const float* __restrict__ w1, const float* __restrict__ b1,
                           const float* __restrict__ w2, const float* __restrict__ b2,
                           float* __restrict__ out2, float* __restrict__ accum) {
    __shared__ float xs[16 * C];    // ao[j][c]
    __shared__ float ys[16 * C];    // out1[j][o]
    __shared__ float hs[16 * HID];  // hid[j][h]
    __shared__ float rs[8];

    const int p0 = blockIdx.x * 16;
    const int t = threadIdx.x;

    #pragma unroll
    for (int it = 0; it < 8; ++it) {
        int e = t + 256 * it;
        xs[e] = ao_t[p0 * C + e];
    }
    __syncthreads();

    const int o = t & 127, half = t >> 7;
    float out1r[8];
    {
        float acc[8] = {0.f, 0.f, 0.f, 0.f, 0.f, 0.f, 0.f, 0.f};
        const float* Wr = w_fc + o * C;
        for (int c = 0; c < C; ++c) {
            float w = Wr[c];
            #pragma unroll
            for (int i = 0; i < 8; ++i) acc[i] += w * xs[(half * 8 + i) * C + c];
        }
        #pragma unroll
        for (int i = 0; i < 8; ++i) {
            out1r[i] = acc[i];
            ys[(half * 8 + i) * C + o] = acc[i];
        }
    }
    __syncthreads();
    {
        // hid: one hidden channel per thread (t in [0,256))
        float acc[16] = {0.f};
        const float* Wr = w1 + t * C;
        for (int c = 0; c < C; ++c) {
            float w = Wr[c];
            #pragma unroll
            for (int j = 0; j < 16; ++j) acc[j] += w * ys[j * C + c];
        }
        float bb = b1[t];
        #pragma unroll
        for (int j = 0; j < 16; ++j) {
            float v = acc[j] + bb;
            hs[j * HID + t] = (v >= 0.f) ? v : 0.2f * v;
        }
    }
    __syncthreads();
    float lsum = 0.f, lsq = 0.f;
    {
        float acc[8] = {0.f, 0.f, 0.f, 0.f, 0.f, 0.f, 0.f, 0.f};
        const float* Wr = w2 + o * HID;
        for (int h = 0; h < HID; ++h) {
            float w = Wr[h];
            #pragma unroll
            for (int i = 0; i < 8; ++i) acc[i] += w * hs[(half * 8 + i) * HID + h];
        }
        float bb = b2[o];
        #pragma unroll
        for (int i = 0; i < 8; ++i) {
            float v = out1r[i] + acc[i] + bb;
            out2[o * HW + p0 + half * 8 + i] = v;
            lsum += v;
            lsq += v * v;
        }
    }
    // block reduction for layernorm stats
    #pragma unroll
    for (int m = 1; m < 64; m <<= 1) {
        lsum += __shfl_xor(lsum, m);
        lsq  += __shfl_xor(lsq, m);
    }
    int wv = t >> 6, ln = t & 63;
    if (ln == 0) { rs[wv] = lsum; rs[4 + wv] = lsq; }
    __syncthreads();
    if (t == 0) {
        atomicAdd(&accum[0], rs[0] + rs[1] + rs[2] + rs[3]);
        atomicAdd(&accum[1], rs[4] + rs[5] + rs[6] + rs[7]);
    }
}

// ---------------- kernel 4: global layernorm (in place on d_out) ----------------
__global__ void norm_kernel(float* __restrict__ out2, const float* __restrict__ accum,
                            const float* __restrict__ gn_w, const float* __restrict__ gn_b) {
    const int gid = blockIdx.x * 256 + threadIdx.x;
    const float invN = 1.f / 2097152.f;
    float mean = accum[0] * invN;
    float var = accum[1] * invN - mean * mean;
    float rstd = rsqrtf(var + 1e-5f);
    int base = gid * 4;
    int o = base >> 14;    // / HW
    float g = gn_w[o] * rstd;
    float b = gn_b[o];
    float4 v = *(const float4*)(out2 + base);
    float4 r;
    r.x = (v.x - mean) * g + b;
    r.y = (v.y - mean) * g + b;
    r.z = (v.z - mean) * g + b;
    r.w = (v.w - mean) * g + b;
    *(float4*)(out2 + base) = r;
}

extern "C" void kernel_launch(void* const* d_in, const int* in_sizes, int n_in,
                              void* d_out, int out_size, void* d_ws, size_t ws_size,
                              hipStream_t stream) {
    const float* query  = (const float*)d_in[0];
    const float* key    = (const float*)d_in[1];
    const float* value  = (const float*)d_in[2];
    const float* deform = (const float*)d_in[3];
    const float* w_q    = (const float*)d_in[4];
    const float* w_k    = (const float*)d_in[5];
    const float* w_v    = (const float*)d_in[6];
    const float* w_fc   = (const float*)d_in[7];
    const float* mlp_w1 = (const float*)d_in[8];
    const float* mlp_b1 = (const float*)d_in[9];
    const float* mlp_w2 = (const float*)d_in[10];
    const float* mlp_b2 = (const float*)d_in[11];
    const float* gn_w   = (const float*)d_in[12];
    const float* gn_b   = (const float*)d_in[13];

    float* out = (float*)d_out;
    float* ws  = (float*)d_ws;

    const size_t T = (size_t)HW * C;   // 2,097,152 floats = 8 MB
    float* q_t  = ws;                  // 8 MB
    float* kv_t = ws + T;              // 16 MB (k|v interleaved per pixel)
    float* ao_t = ws + 3 * T;          // 8 MB
    float* acc  = ws + 4 * T;

    zero_acc_kernel<<<1, 1, 0, stream>>>(acc);
    qkv_kernel<<<1024, 256, 0, stream>>>(query, key, value, w_q, w_k, w_v, q_t, kv_t);
    attn_kernel<<<1024, 256, 0, stream>>>(q_t, kv_t, deform, ao_t);
    mlp_kernel<<<1024, 256, 0, stream>>>(ao_t, w_fc, mlp_w1, mlp_b1, mlp_w2, mlp_b2, out, acc);
    norm_kernel<<<2048, 256, 0, stream>>>(out, acc, gn_w, gn_b);
}

// Round 5
// 209.205 us; speedup vs baseline: 3.1559x; 3.1559x over previous
//
#include <hip/hip_runtime.h>
#include <hip/hip_bf16.h>

#define HW 16384
#define W 128
#define C 128
#define HID 256

// ---------------- kernel 0: zero the stat accumulators ----------------
__global__ void zero_acc_kernel(float* acc) {
    acc[0] = 0.f;
    acc[1] = 0.f;
}

// ---------------- kernel 1: q/k/v 1x1 convs ----------------
// q -> q_t[pix][C]; k,v -> kv_t[pix][256] (k in [0,128), v in [128,256))
// grid 1024, block 256. 16 pixels per block.
__global__ void qkv_kernel(const float* __restrict__ q_in, const float* __restrict__ k_in,
                           const float* __restrict__ v_in,
                           const float* __restrict__ w_q, const float* __restrict__ w_k,
                           const float* __restrict__ w_v,
                           float* __restrict__ q_t, float* __restrict__ kv_t) {
    __shared__ float xs[3][C * 16];
    const int p0 = blockIdx.x * 16;
    const int t = threadIdx.x;

    #pragma unroll
    for (int it = 0; it < 8; ++it) {
        int e = t + 256 * it;          // e = c*16 + j
        int c = e >> 4, j = e & 15;
        xs[0][e] = q_in[c * HW + p0 + j];
        xs[1][e] = k_in[c * HW + p0 + j];
        xs[2][e] = v_in[c * HW + p0 + j];
    }
    __syncthreads();

    const int o = t & 127, half = t >> 7;
    const float* Ws[3] = {w_q, w_k, w_v};

    #pragma unroll
    for (int m = 0; m < 3; ++m) {
        float acc[8] = {0.f, 0.f, 0.f, 0.f, 0.f, 0.f, 0.f, 0.f};
        const float* Wr = Ws[m] + o * C;
        const float* xb = &xs[m][half * 8];
        for (int c = 0; c < C; ++c) {
            float w = Wr[c];
            const float* xr = xb + c * 16;
            #pragma unroll
            for (int i = 0; i < 8; ++i) acc[i] += w * xr[i];
        }
        #pragma unroll
        for (int i = 0; i < 8; ++i) {
            int p = p0 + half * 8 + i;
            if (m == 0)      q_t[p * C + o] = acc[i];
            else if (m == 1) kv_t[p * 256 + o] = acc[i];
            else             kv_t[p * 256 + 128 + o] = acc[i];
        }
    }
}

// ---------------- kernel 2: deformable sampling + attention (online softmax) ----------------
// 1024 blocks x 256 threads, 2 passes (job = 8 consecutive-x pixels, 32 thr/pixel,
// 4 ch/thread, float4 gathers). Tap loop is NOT unrolled: keeps the live set
// ~40 VGPRs so nothing spills; latency is hidden by TLP, not unroll-ILP.
__global__ __launch_bounds__(256, 2)
void attn_kernel(const float* __restrict__ q_t, const float* __restrict__ kv_t,
                 const float* __restrict__ deform, float* __restrict__ ao_t) {
    __shared__ int   s_off[8][25][4];
    __shared__ float s_w[8][25][4];

    const int t = threadIdx.x;
    const int pi = t >> 5;     // pixel within job
    const int g = t & 31;      // channel group (4 channels each)
    const char* kvb = (const char*)kv_t;
    const int go = g * 16;

    #pragma unroll 1
    for (int pass = 0; pass < 2; ++pass) {
        const int jj = blockIdx.x + pass * 1024;
        const int y = jj >> 4;
        const int x = ((jj & 15) << 3) + pi;
        const int pix = y * W + x;

        if (pass) __syncthreads();    // protect LDS reuse across jobs

        if (g < 25) {
            float dx = deform[pix];
            float dy = deform[HW + pix];
            int iy = g / 5, ix = g - iy * 5;
            float vx = (float)x + (float)(ix - 2) + dx;
            float vy = (float)y + (float)(iy - 2) + dy;
            float x0f = floorf(vx), y0f = floorf(vy);
            float fx = vx - x0f, fy = vy - y0f;
            float wx[2] = {1.f - fx, fx};
            float wy[2] = {1.f - fy, fy};
            #pragma unroll
            for (int cy = 0; cy < 2; ++cy) {
                #pragma unroll
                for (int cx = 0; cx < 2; ++cx) {
                    float xf = x0f + (float)cx;
                    float yf = y0f + (float)cy;
                    bool valid = (xf >= 0.f) & (xf <= 127.f) & (yf >= 0.f) & (yf <= 127.f);
                    int xi = min(max((int)xf, 0), 127);
                    int yi = min(max((int)yf, 0), 127);
                    s_off[pi][g][cy * 2 + cx] = (yi * W + xi) * 1024;   // byte offset of kv row
                    s_w[pi][g][cy * 2 + cx] = valid ? wx[cx] * wy[cy] : 0.f;
                }
            }
        }
        __syncthreads();

        float4 q4 = *(const float4*)(q_t + (size_t)pix * C + 4 * g);
        q4.x *= 0.25f; q4.y *= 0.25f; q4.z *= 0.25f; q4.w *= 0.25f;   // 1/sqrt(16)

        float m = -1e30f;
        float sum = 0.f;
        float4 oc = {0.f, 0.f, 0.f, 0.f};

        #pragma unroll 1
        for (int p = 0; p < 25; ++p) {
            int4   off = *(const int4*)&s_off[pi][p][0];
            float4 w   = *(const float4*)&s_w[pi][p][0];
            const char* a0 = kvb + off.x + go;
            const char* a1 = kvb + off.y + go;
            const char* a2 = kvb + off.z + go;
            const char* a3 = kvb + off.w + go;

            // k-phase
            float4 k0 = *(const float4*)(a0);
            float4 k1 = *(const float4*)(a1);
            float4 k2 = *(const float4*)(a2);
            float4 k3 = *(const float4*)(a3);
            float4 ks;
            ks.x = w.x * k0.x + w.y * k1.x + w.z * k2.x + w.w * k3.x;
            ks.y = w.x * k0.y + w.y * k1.y + w.z * k2.y + w.w * k3.y;
            ks.z = w.x * k0.z + w.y * k1.z + w.z * k2.z + w.w * k3.z;
            ks.w = w.x * k0.w + w.y * k1.w + w.z * k2.w + w.w * k3.w;
            float sp = q4.x * ks.x + q4.y * ks.y + q4.z * ks.z + q4.w * ks.w;
            sp += __shfl_xor(sp, 1);
            sp += __shfl_xor(sp, 2);    // 4-thread group = one head (16 channels)

            // v-phase (same addresses + 512B immediate)
            float4 v0 = *(const float4*)(a0 + 512);
            float4 v1 = *(const float4*)(a1 + 512);
            float4 v2 = *(const float4*)(a2 + 512);
            float4 v3 = *(const float4*)(a3 + 512);
            float4 vs;
            vs.x = w.x * v0.x + w.y * v1.x + w.z * v2.x + w.w * v3.x;
            vs.y = w.x * v0.y + w.y * v1.y + w.z * v2.y + w.w * v3.y;
            vs.z = w.x * v0.z + w.y * v1.z + w.z * v2.z + w.w * v3.z;
            vs.w = w.x * v0.w + w.y * v1.w + w.z * v2.w + w.w * v3.w;

            float mn   = fmaxf(m, sp);
            float corr = __expf(m - mn);
            float e    = __expf(sp - mn);
            sum  = sum * corr + e;
            oc.x = oc.x * corr + e * vs.x;
            oc.y = oc.y * corr + e * vs.y;
            oc.z = oc.z * corr + e * vs.z;
            oc.w = oc.w * corr + e * vs.w;
            m = mn;
        }

        float inv = 1.f / sum;
        oc.x *= inv; oc.y *= inv; oc.z *= inv; oc.w *= inv;
        *(float4*)(ao_t + (size_t)pix * C + 4 * g) = oc;
    }
}

// ---------------- kernel 3: fc + MLP + residual + stats ----------------
// grid 1024, block 256. 16 pixels per block. out2 goes straight into d_out [C][HW].
__global__ void mlp_kernel(const float* __restrict__ ao_t, const float* __restrict__ w_fc,
                           const float* __restrict__ w1, const float* __restrict__ b1,
                           const float* __restrict__ w2, const float* __restrict__ b2,
                           float* __restrict__ out2, float* __restrict__ accum) {
    __shared__ float xs[16 * C];    // ao[j][c]
    __shared__ float ys[16 * C];    // out1[j][o]
    __shared__ float hs[16 * HID];  // hid[j][h]
    __shared__ float rs[8];

    const int p0 = blockIdx.x * 16;
    const int t = threadIdx.x;

    #pragma unroll
    for (int it = 0; it < 8; ++it) {
        int e = t + 256 * it;
        xs[e] = ao_t[p0 * C + e];
    }
    __syncthreads();

    const int o = t & 127, half = t >> 7;
    float out1r[8];
    {
        float acc[8] = {0.f, 0.f, 0.f, 0.f, 0.f, 0.f, 0.f, 0.f};
        const float* Wr = w_fc + o * C;
        for (int c = 0; c < C; ++c) {
            float w = Wr[c];
            #pragma unroll
            for (int i = 0; i < 8; ++i) acc[i] += w * xs[(half * 8 + i) * C + c];
        }
        #pragma unroll
        for (int i = 0; i < 8; ++i) {
            out1r[i] = acc[i];
            ys[(half * 8 + i) * C + o] = acc[i];
        }
    }
    __syncthreads();
    {
        // hid: one hidden channel per thread (t in [0,256))
        float acc[16] = {0.f};
        const float* Wr = w1 + t * C;
        for (int c = 0; c < C; ++c) {
            float w = Wr[c];
            #pragma unroll
            for (int j = 0; j < 16; ++j) acc[j] += w * ys[j * C + c];
        }
        float bb = b1[t];
        #pragma unroll
        for (int j = 0; j < 16; ++j) {
            float v = acc[j] + bb;
            hs[j * HID + t] = (v >= 0.f) ? v : 0.2f * v;
        }
    }
    __syncthreads();
    float lsum = 0.f, lsq = 0.f;
    {
        float acc[8] = {0.f, 0.f, 0.f, 0.f, 0.f, 0.f, 0.f, 0.f};
        const float* Wr = w2 + o * HID;
        for (int h = 0; h < HID; ++h) {
            float w = Wr[h];
            #pragma unroll
            for (int i = 0; i < 8; ++i) acc[i] += w * hs[(half * 8 + i) * HID + h];
        }
        float bb = b2[o];
        #pragma unroll
        for (int i = 0; i < 8; ++i) {
            float v = out1r[i] + acc[i] + bb;
            out2[o * HW + p0 + half * 8 + i] = v;
            lsum += v;
            lsq += v * v;
        }
    }
    // block reduction for layernorm stats
    #pragma unroll
    for (int m = 1; m < 64; m <<= 1) {
        lsum += __shfl_xor(lsum, m);
        lsq  += __shfl_xor(lsq, m);
    }
    int wv = t >> 6, ln = t & 63;
    if (ln == 0) { rs[wv] = lsum; rs[4 + wv] = lsq; }
    __syncthreads();
    if (t == 0) {
        atomicAdd(&accum[0], rs[0] + rs[1] + rs[2] + rs[3]);
        atomicAdd(&accum[1], rs[4] + rs[5] + rs[6] + rs[7]);
    }
}

// ---------------- kernel 4: global layernorm (in place on d_out) ----------------
__global__ void norm_kernel(float* __restrict__ out2, const float* __restrict__ accum,
                            const float* __restrict__ gn_w, const float* __restrict__ gn_b) {
    const int gid = blockIdx.x * 256 + threadIdx.x;
    const float invN = 1.f / 2097152.f;
    float mean = accum[0] * invN;
    float var = accum[1] * invN - mean * mean;
    float rstd = rsqrtf(var + 1e-5f);
    int base = gid * 4;
    int o = base >> 14;    // / HW
    float g = gn_w[o] * rstd;
    float b = gn_b[o];
    float4 v = *(const float4*)(out2 + base);
    float4 r;
    r.x = (v.x - mean) * g + b;
    r.y = (v.y - mean) * g + b;
    r.z = (v.z - mean) * g + b;
    r.w = (v.w - mean) * g + b;
    *(float4*)(out2 + base) = r;
}

extern "C" void kernel_launch(void* const* d_in, const int* in_sizes, int n_in,
                              void* d_out, int out_size, void* d_ws, size_t ws_size,
                              hipStream_t stream) {
    const float* query  = (const float*)d_in[0];
    const float* key    = (const float*)d_in[1];
    const float* value  = (const float*)d_in[2];
    const float* deform = (const float*)d_in[3];
    const float* w_q    = (const float*)d_in[4];
    const float* w_k    = (const float*)d_in[5];
    const float* w_v    = (const float*)d_in[6];
    const float* w_fc   = (const float*)d_in[7];
    const float* mlp_w1 = (const float*)d_in[8];
    const float* mlp_b1 = (const float*)d_in[9];
    const float* mlp_w2 = (const float*)d_in[10];
    const float* mlp_b2 = (const float*)d_in[11];
    const float* gn_w   = (const float*)d_in[12];
    const float* gn_b   = (const float*)d_in[13];

    float* out = (float*)d_out;
    float* ws  = (float*)d_ws;

    const size_t T = (size_t)HW * C;   // 2,097,152 floats = 8 MB
    float* q_t  = ws;                  // 8 MB
    float* kv_t = ws + T;              // 16 MB (k|v interleaved per pixel)
    float* ao_t = ws + 3 * T;          // 8 MB
    float* acc  = ws + 4 * T;

    zero_acc_kernel<<<1, 1, 0, stream>>>(acc);
    qkv_kernel<<<1024, 256, 0, stream>>>(query, key, value, w_q, w_k, w_v, q_t, kv_t);
    attn_kernel<<<1024, 256, 0, stream>>>(q_t, kv_t, deform, ao_t);
    mlp_kernel<<<1024, 256, 0, stream>>>(ao_t, w_fc, mlp_w1, mlp_b1, mlp_w2, mlp_b2, out, acc);
    norm_kernel<<<2048, 256, 0, stream>>>(out, acc, gn_w, gn_b);
}

// Round 6
// 169.459 us; speedup vs baseline: 3.8961x; 1.2345x over previous
//
#include <hip/hip_runtime.h>
#include <hip/hip_bf16.h>

#define HW 16384
#define W 128
#define C 128
#define HID 256

typedef __attribute__((ext_vector_type(8))) short short8v;
typedef __attribute__((ext_vector_type(4))) float f32x4;

__device__ __forceinline__ unsigned short f2bf(float f) {
    union { float f; unsigned u; } x; x.f = f;
    unsigned r = x.u + 0x7FFF + ((x.u >> 16) & 1);
    return (unsigned short)(r >> 16);
}

// ---------------- kernel 0: zero the stat accumulators ----------------
__global__ void zero_acc_kernel(float* acc) {
    acc[0] = 0.f;
    acc[1] = 0.f;
}

// ---------------- kernel 1: convert all weights to bf16 ----------------
// layout in wb: wq[16384] wk[16384] wv[16384] wfc[16384] w1[32768] w2[32768]
__global__ void prep_weights(const float* __restrict__ wq, const float* __restrict__ wk,
                             const float* __restrict__ wv, const float* __restrict__ wfc,
                             const float* __restrict__ w1, const float* __restrict__ w2,
                             unsigned short* __restrict__ wb) {
    int i = blockIdx.x * 256 + threadIdx.x;   // 0..131071
    float v;
    if (i < 16384)       v = wq[i];
    else if (i < 32768)  v = wk[i - 16384];
    else if (i < 49152)  v = wv[i - 32768];
    else if (i < 65536)  v = wfc[i - 49152];
    else if (i < 98304)  v = w1[i - 65536];
    else                 v = w2[i - 98304];
    wb[i] = f2bf(v);
}

// ---------------- kernel 2: q/k/v 1x1 convs via MFMA ----------------
// 512 blocks x 256 thr; 32 pixels/block; 4 waves = (2 pixel-halves x 2 m-halves).
// Stages x tiles to LDS as bf16 (XOR-swizzled), B-frags via ds_read_b128,
// A-frags (bf16 weights) straight from global. Outputs fp32 q_t/kv_t for attn.
__global__ __launch_bounds__(256, 2)
void qkv_mfma(const float* __restrict__ q_in, const float* __restrict__ k_in,
              const float* __restrict__ v_in, const unsigned short* __restrict__ wb,
              float* __restrict__ q_t, float* __restrict__ kv_t) {
    __shared__ unsigned short lx[3][32 * 128];
    const int t = threadIdx.x;
    const int p0 = blockIdx.x * 32;
    const int lane = t & 63, row16 = lane & 15, g = lane >> 4;
    const int w = t >> 6, nh = w & 1, mh = w >> 1;
    const int ploc = nh * 16 + row16;
    const int pix = p0 + ploc;

    const float* ins[3] = {q_in, k_in, v_in};
    #pragma unroll
    for (int m = 0; m < 3; ++m) {
        #pragma unroll
        for (int it = 0; it < 16; ++it) {
            int e = t + 256 * it;          // 0..4095
            int p = e & 31, c = e >> 5;
            float v = ins[m][c * HW + p0 + p];
            lx[m][p * 128 + (c ^ ((p & 7) << 3))] = f2bf(v);
        }
    }
    __syncthreads();

    const int swz = (ploc & 7) << 3;
    #pragma unroll
    for (int m = 0; m < 3; ++m) {
        const unsigned short* wseg = wb + m * 16384;
        f32x4 acc[4] = {};
        #pragma unroll
        for (int kk = 0; kk < 4; ++kk) {
            short8v b = *(const short8v*)&lx[m][ploc * 128 + ((kk * 32 + g * 8) ^ swz)];
            #pragma unroll
            for (int f = 0; f < 4; ++f) {
                short8v a = *(const short8v*)&wseg[(mh * 64 + f * 16 + row16) * 128 + kk * 32 + g * 8];
                acc[f] = __builtin_amdgcn_mfma_f32_16x16x32_bf16(a, b, acc[f], 0, 0, 0);
            }
        }
        #pragma unroll
        for (int f = 0; f < 4; ++f) {
            int o = mh * 64 + f * 16 + g * 4;
            float4 st = make_float4(acc[f][0], acc[f][1], acc[f][2], acc[f][3]);
            if (m == 0)      *(float4*)&q_t[(size_t)pix * 128 + o] = st;
            else if (m == 1) *(float4*)&kv_t[(size_t)pix * 256 + o] = st;
            else             *(float4*)&kv_t[(size_t)pix * 256 + 128 + o] = st;
        }
    }
}

// ---------------- kernel 3: deformable sampling + attention (online softmax) ----------------
// unchanged structure from round 5 (the 209us version); output now bf16 [pix][128].
__global__ __launch_bounds__(256, 2)
void attn_kernel(const float* __restrict__ q_t, const float* __restrict__ kv_t,
                 const float* __restrict__ deform, unsigned short* __restrict__ ao_t) {
    __shared__ int   s_off[8][25][4];
    __shared__ float s_w[8][25][4];

    const int t = threadIdx.x;
    const int pi = t >> 5;
    const int g = t & 31;
    const char* kvb = (const char*)kv_t;
    const int go = g * 16;

    #pragma unroll 1
    for (int pass = 0; pass < 2; ++pass) {
        const int jj = blockIdx.x + pass * 1024;
        const int y = jj >> 4;
        const int x = ((jj & 15) << 3) + pi;
        const int pix = y * W + x;

        if (pass) __syncthreads();

        if (g < 25) {
            float dx = deform[pix];
            float dy = deform[HW + pix];
            int iy = g / 5, ix = g - iy * 5;
            float vx = (float)x + (float)(ix - 2) + dx;
            float vy = (float)y + (float)(iy - 2) + dy;
            float x0f = floorf(vx), y0f = floorf(vy);
            float fx = vx - x0f, fy = vy - y0f;
            float wx[2] = {1.f - fx, fx};
            float wy[2] = {1.f - fy, fy};
            #pragma unroll
            for (int cy = 0; cy < 2; ++cy) {
                #pragma unroll
                for (int cx = 0; cx < 2; ++cx) {
                    float xf = x0f + (float)cx;
                    float yf = y0f + (float)cy;
                    bool valid = (xf >= 0.f) & (xf <= 127.f) & (yf >= 0.f) & (yf <= 127.f);
                    int xi = min(max((int)xf, 0), 127);
                    int yi = min(max((int)yf, 0), 127);
                    s_off[pi][g][cy * 2 + cx] = (yi * W + xi) * 1024;
                    s_w[pi][g][cy * 2 + cx] = valid ? wx[cx] * wy[cy] : 0.f;
                }
            }
        }
        __syncthreads();

        float4 q4 = *(const float4*)(q_t + (size_t)pix * C + 4 * g);
        q4.x *= 0.25f; q4.y *= 0.25f; q4.z *= 0.25f; q4.w *= 0.25f;

        float m = -1e30f;
        float sum = 0.f;
        float4 oc = {0.f, 0.f, 0.f, 0.f};

        #pragma unroll 1
        for (int p = 0; p < 25; ++p) {
            int4   off = *(const int4*)&s_off[pi][p][0];
            float4 w   = *(const float4*)&s_w[pi][p][0];
            const char* a0 = kvb + off.x + go;
            const char* a1 = kvb + off.y + go;
            const char* a2 = kvb + off.z + go;
            const char* a3 = kvb + off.w + go;

            float4 k0 = *(const float4*)(a0);
            float4 k1 = *(const float4*)(a1);
            float4 k2 = *(const float4*)(a2);
            float4 k3 = *(const float4*)(a3);
            float4 ks;
            ks.x = w.x * k0.x + w.y * k1.x + w.z * k2.x + w.w * k3.x;
            ks.y = w.x * k0.y + w.y * k1.y + w.z * k2.y + w.w * k3.y;
            ks.z = w.x * k0.z + w.y * k1.z + w.z * k2.z + w.w * k3.z;
            ks.w = w.x * k0.w + w.y * k1.w + w.z * k2.w + w.w * k3.w;
            float sp = q4.x * ks.x + q4.y * ks.y + q4.z * ks.z + q4.w * ks.w;
            sp += __shfl_xor(sp, 1);
            sp += __shfl_xor(sp, 2);

            float4 v0 = *(const float4*)(a0 + 512);
            float4 v1 = *(const float4*)(a1 + 512);
            float4 v2 = *(const float4*)(a2 + 512);
            float4 v3 = *(const float4*)(a3 + 512);
            float4 vs;
            vs.x = w.x * v0.x + w.y * v1.x + w.z * v2.x + w.w * v3.x;
            vs.y = w.x * v0.y + w.y * v1.y + w.z * v2.y + w.w * v3.y;
            vs.z = w.x * v0.z + w.y * v1.z + w.z * v2.z + w.w * v3.z;
            vs.w = w.x * v0.w + w.y * v1.w + w.z * v2.w + w.w * v3.w;

            float mn   = fmaxf(m, sp);
            float corr = __expf(m - mn);
            float e    = __expf(sp - mn);
            sum  = sum * corr + e;
            oc.x = oc.x * corr + e * vs.x;
            oc.y = oc.y * corr + e * vs.y;
            oc.z = oc.z * corr + e * vs.z;
            oc.w = oc.w * corr + e * vs.w;
            m = mn;
        }

        float inv = 1.f / sum;
        ushort4 ob;
        ob.x = f2bf(oc.x * inv);
        ob.y = f2bf(oc.y * inv);
        ob.z = f2bf(oc.z * inv);
        ob.w = f2bf(oc.w * inv);
        *(ushort4*)(ao_t + (size_t)pix * C + 4 * g) = ob;
    }
}

// ---------------- kernel 4: fc + MLP + residual + stats via MFMA ----------------
// 512 blocks x 256 thr; 32 px/block; chain of 3 GEMMs, intermediates bf16 in LDS.
// Residual out1 stays in fp32 accumulator registers (same m-mapping as GEMM3).
__global__ __launch_bounds__(256, 2)
void mlp_mfma(const unsigned short* __restrict__ ao_t, const unsigned short* __restrict__ wb,
              const float* __restrict__ b1, const float* __restrict__ b2,
              float* __restrict__ out2, float* __restrict__ accum) {
    __shared__ unsigned short l1[32 * 128];   // out1 bf16, swizzled
    __shared__ unsigned short lh[32 * 256];   // hid  bf16, swizzled
    const int t = threadIdx.x;
    const int p0 = blockIdx.x * 32;
    const int lane = t & 63, row16 = lane & 15, g = lane >> 4;
    const int w = t >> 6, nh = w & 1, mh = w >> 1;
    const int ploc = nh * 16 + row16;
    const int pix = p0 + ploc;
    const int swz = (ploc & 7) << 3;
    const unsigned short* wfc_b = wb + 49152;
    const unsigned short* w1_b  = wb + 65536;
    const unsigned short* w2_b  = wb + 98304;

    // GEMM1: out1 = wfc . ao   (M=128 -> 64/wave, K=128; B straight from global)
    f32x4 acc1[4] = {};
    #pragma unroll
    for (int kk = 0; kk < 4; ++kk) {
        short8v b = *(const short8v*)&ao_t[(size_t)pix * 128 + kk * 32 + g * 8];
        #pragma unroll
        for (int f = 0; f < 4; ++f) {
            short8v a = *(const short8v*)&wfc_b[(mh * 64 + f * 16 + row16) * 128 + kk * 32 + g * 8];
            acc1[f] = __builtin_amdgcn_mfma_f32_16x16x32_bf16(a, b, acc1[f], 0, 0, 0);
        }
    }
    #pragma unroll
    for (int f = 0; f < 4; ++f)
        #pragma unroll
        for (int r = 0; r < 4; ++r) {
            int o = mh * 64 + f * 16 + g * 4 + r;
            l1[ploc * 128 + (o ^ swz)] = f2bf(acc1[f][r]);
        }
    __syncthreads();

    // GEMM2: hid = leaky(w1 . out1 + b1)   (M=256 -> 128/wave, K=128)
    f32x4 acc2[8] = {};
    #pragma unroll
    for (int kk = 0; kk < 4; ++kk) {
        short8v b = *(const short8v*)&l1[ploc * 128 + ((kk * 32 + g * 8) ^ swz)];
        #pragma unroll
        for (int f = 0; f < 8; ++f) {
            short8v a = *(const short8v*)&w1_b[(mh * 128 + f * 16 + row16) * 128 + kk * 32 + g * 8];
            acc2[f] = __builtin_amdgcn_mfma_f32_16x16x32_bf16(a, b, acc2[f], 0, 0, 0);
        }
    }
    #pragma unroll
    for (int f = 0; f < 8; ++f)
        #pragma unroll
        for (int r = 0; r < 4; ++r) {
            int h = mh * 128 + f * 16 + g * 4 + r;
            float v = acc2[f][r] + b1[h];
            v = (v >= 0.f) ? v : 0.2f * v;
            lh[ploc * 256 + (h ^ swz)] = f2bf(v);
        }
    __syncthreads();

    // GEMM3: out2 = w2 . hid + b2 + out1   (M=128 -> 64/wave, K=256)
    f32x4 acc3[4] = {};
    #pragma unroll
    for (int kk = 0; kk < 8; ++kk) {
        short8v b = *(const short8v*)&lh[ploc * 256 + ((kk * 32 + g * 8) ^ swz)];
        #pragma unroll
        for (int f = 0; f < 4; ++f) {
            short8v a = *(const short8v*)&w2_b[(mh * 64 + f * 16 + row16) * 256 + kk * 32 + g * 8];
            acc3[f] = __builtin_amdgcn_mfma_f32_16x16x32_bf16(a, b, acc3[f], 0, 0, 0);
        }
    }

    float lsum = 0.f, lsq = 0.f;
    #pragma unroll
    for (int f = 0; f < 4; ++f) {
        int ob = mh * 64 + f * 16 + g * 4;
        #pragma unroll
        for (int r = 0; r < 4; ++r) {
            float v = acc3[f][r] + acc1[f][r] + b2[ob + r];
            out2[(size_t)(ob + r) * HW + pix] = v;
            lsum += v;
            lsq += v * v;
        }
    }
    #pragma unroll
    for (int s = 1; s < 64; s <<= 1) {
        lsum += __shfl_xor(lsum, s);
        lsq  += __shfl_xor(lsq, s);
    }
    if (lane == 0) {
        atomicAdd(&accum[0], lsum);
        atomicAdd(&accum[1], lsq);
    }
}

// ---------------- kernel 5: global layernorm (in place on d_out) ----------------
__global__ void norm_kernel(float* __restrict__ out2, const float* __restrict__ accum,
                            const float* __restrict__ gn_w, const float* __restrict__ gn_b) {
    const int gid = blockIdx.x * 256 + threadIdx.x;
    const float invN = 1.f / 2097152.f;
    float mean = accum[0] * invN;
    float var = accum[1] * invN - mean * mean;
    float rstd = rsqrtf(var + 1e-5f);
    int base = gid * 4;
    int o = base >> 14;
    float g = gn_w[o] * rstd;
    float b = gn_b[o];
    float4 v = *(const float4*)(out2 + base);
    float4 r;
    r.x = (v.x - mean) * g + b;
    r.y = (v.y - mean) * g + b;
    r.z = (v.z - mean) * g + b;
    r.w = (v.w - mean) * g + b;
    *(float4*)(out2 + base) = r;
}

extern "C" void kernel_launch(void* const* d_in, const int* in_sizes, int n_in,
                              void* d_out, int out_size, void* d_ws, size_t ws_size,
                              hipStream_t stream) {
    const float* query  = (const float*)d_in[0];
    const float* key    = (const float*)d_in[1];
    const float* value  = (const float*)d_in[2];
    const float* deform = (const float*)d_in[3];
    const float* w_q    = (const float*)d_in[4];
    const float* w_k    = (const float*)d_in[5];
    const float* w_v    = (const float*)d_in[6];
    const float* w_fc   = (const float*)d_in[7];
    const float* mlp_w1 = (const float*)d_in[8];
    const float* mlp_b1 = (const float*)d_in[9];
    const float* mlp_w2 = (const float*)d_in[10];
    const float* mlp_b2 = (const float*)d_in[11];
    const float* gn_w   = (const float*)d_in[12];
    const float* gn_b   = (const float*)d_in[13];

    float* out = (float*)d_out;
    char* wsb  = (char*)d_ws;

    // ws layout (bytes): q_t f32 [0,8M) | kv_t f32 [8M,24M) | ao bf16 [24M,28M)
    //                    | wb bf16 [28M, 28M+256K) | acc [29M, +8)
    float* q_t = (float*)wsb;
    float* kv_t = (float*)(wsb + ((size_t)8 << 20));
    unsigned short* ao_t = (unsigned short*)(wsb + ((size_t)24 << 20));
    unsigned short* wb = (unsigned short*)(wsb + ((size_t)28 << 20));
    float* acc = (float*)(wsb + ((size_t)29 << 20));

    zero_acc_kernel<<<1, 1, 0, stream>>>(acc);
    prep_weights<<<512, 256, 0, stream>>>(w_q, w_k, w_v, w_fc, mlp_w1, mlp_w2, wb);
    qkv_mfma<<<512, 256, 0, stream>>>(query, key, value, wb, q_t, kv_t);
    attn_kernel<<<1024, 256, 0, stream>>>(q_t, kv_t, deform, ao_t);
    mlp_mfma<<<512, 256, 0, stream>>>(ao_t, wb, mlp_b1, mlp_b2, out, acc);
    norm_kernel<<<2048, 256, 0, stream>>>(out, acc, gn_w, gn_b);
}

// Round 7
// 146.110 us; speedup vs baseline: 4.5187x; 1.1598x over previous
//
#include <hip/hip_runtime.h>
#include <hip/hip_bf16.h>

#define HW 16384
#define W 128
#define C 128
#define HID 256

typedef __attribute__((ext_vector_type(8))) short short8v;
typedef __attribute__((ext_vector_type(4))) float f32x4;

__device__ __forceinline__ unsigned short f2bf(float f) {
    union { float f; unsigned u; } x; x.f = f;
    unsigned r = x.u + 0x7FFF + ((x.u >> 16) & 1);
    return (unsigned short)(r >> 16);
}
__device__ __forceinline__ float bf2f(unsigned short b) {
    union { unsigned u; float f; } x; x.u = ((unsigned)b) << 16;
    return x.f;
}

// Stage a 32KB weight panel (2048 granules of 16B) global->LDS.
// Linear coalesced global read; swizzled LDS write: granule col ^= (row&7).
// RSH = log2(granules per row): 4 for K=128 rows, 5 for K=256 rows.
template<int RSH>
__device__ __forceinline__ void stage32(const unsigned short* __restrict__ src,
                                        unsigned short* lds, int t) {
    #pragma unroll
    for (int c = 0; c < 8; ++c) {
        int gi = c * 256 + t;
        int row = gi >> RSH, colg = gi & ((1 << RSH) - 1);
        short8v v = *(const short8v*)(src + (size_t)gi * 8);
        *(short8v*)(lds + (size_t)(((row << RSH) + (colg ^ (row & 7))) << 3)) = v;
    }
}

// ---------------- kernel 0: zero the stat accumulators ----------------
__global__ void zero_acc_kernel(float* acc) {
    acc[0] = 0.f;
    acc[1] = 0.f;
}

// ---------------- kernel 1: convert all weights to bf16 ----------------
// layout in wb: wq[16384] wk[16384] wv[16384] wfc[16384] w1[32768] w2[32768]
__global__ void prep_weights(const float* __restrict__ wq, const float* __restrict__ wk,
                             const float* __restrict__ wv, const float* __restrict__ wfc,
                             const float* __restrict__ w1, const float* __restrict__ w2,
                             unsigned short* __restrict__ wb) {
    int i = blockIdx.x * 256 + threadIdx.x;   // 0..131071
    float v;
    if (i < 16384)       v = wq[i];
    else if (i < 32768)  v = wk[i - 16384];
    else if (i < 49152)  v = wv[i - 32768];
    else if (i < 65536)  v = wfc[i - 49152];
    else if (i < 98304)  v = w1[i - 65536];
    else                 v = w2[i - 98304];
    wb[i] = f2bf(v);
}

// ---------------- kernel 2: q/k/v 1x1 convs via MFMA, LDS-staged weights ----------------
// 512 blocks x 256 thr; 32 pixels/block; phases: stage w -> GEMM, for q,k,v.
__global__ __launch_bounds__(256, 2)
void qkv_mfma(const float* __restrict__ q_in, const float* __restrict__ k_in,
              const float* __restrict__ v_in, const unsigned short* __restrict__ wb,
              float* __restrict__ q_t, float* __restrict__ kv_t) {
    __shared__ unsigned short lx[3][32 * 128];   // 24 KB inputs (pixel-swizzled)
    __shared__ unsigned short wbuf[16384];       // 32 KB weight panel
    const int t = threadIdx.x;
    const int p0 = blockIdx.x * 32;
    const int lane = t & 63, row16 = lane & 15, g = lane >> 4;
    const int w = t >> 6, nh = w & 1, mh = w >> 1;
    const int ploc = nh * 16 + row16;
    const int pix = p0 + ploc;
    const int swz = (ploc & 7) << 3;

    stage32<4>(wb, wbuf, t);    // wq, in flight during x-tile conversion

    const float* ins[3] = {q_in, k_in, v_in};
    #pragma unroll
    for (int m = 0; m < 3; ++m) {
        #pragma unroll
        for (int it = 0; it < 16; ++it) {
            int e = t + 256 * it;          // 0..4095
            int p = e & 31, c = e >> 5;
            lx[m][p * 128 + (c ^ ((p & 7) << 3))] = f2bf(ins[m][c * HW + p0 + p]);
        }
    }

    #pragma unroll 1
    for (int m = 0; m < 3; ++m) {
        if (m > 0) {
            __syncthreads();               // previous GEMM done reading wbuf
            stage32<4>(wb + m * 16384, wbuf, t);
        }
        __syncthreads();                   // staging (and lx on m=0) visible

        f32x4 acc[4] = {};
        #pragma unroll
        for (int kk = 0; kk < 4; ++kk) {
            short8v b = *(const short8v*)&lx[m][ploc * 128 + ((kk * 32 + g * 8) ^ swz)];
            #pragma unroll
            for (int f = 0; f < 4; ++f) {
                int row = mh * 64 + f * 16 + row16;
                short8v a = *(const short8v*)&wbuf[(row << 7) + (((kk * 4 + g) ^ (row & 7)) << 3)];
                acc[f] = __builtin_amdgcn_mfma_f32_16x16x32_bf16(a, b, acc[f], 0, 0, 0);
            }
        }
        #pragma unroll
        for (int f = 0; f < 4; ++f) {
            int o = mh * 64 + f * 16 + g * 4;
            float4 st = make_float4(acc[f][0], acc[f][1], acc[f][2], acc[f][3]);
            if (m == 0)      *(float4*)&q_t[(size_t)pix * 128 + o] = st;
            else if (m == 1) *(float4*)&kv_t[(size_t)pix * 256 + o] = st;
            else             *(float4*)&kv_t[(size_t)pix * 256 + 128 + o] = st;
        }
    }
}

// ---------------- kernel 3: deformable sampling + attention (online softmax) ----------------
__global__ __launch_bounds__(256, 2)
void attn_kernel(const float* __restrict__ q_t, const float* __restrict__ kv_t,
                 const float* __restrict__ deform, unsigned short* __restrict__ ao_t) {
    __shared__ int   s_off[8][25][4];
    __shared__ float s_w[8][25][4];

    const int t = threadIdx.x;
    const int pi = t >> 5;
    const int g = t & 31;
    const char* kvb = (const char*)kv_t;
    const int go = g * 16;

    #pragma unroll 1
    for (int pass = 0; pass < 2; ++pass) {
        const int jj = blockIdx.x + pass * 1024;
        const int y = jj >> 4;
        const int x = ((jj & 15) << 3) + pi;
        const int pix = y * W + x;

        if (pass) __syncthreads();

        if (g < 25) {
            float dx = deform[pix];
            float dy = deform[HW + pix];
            int iy = g / 5, ix = g - iy * 5;
            float vx = (float)x + (float)(ix - 2) + dx;
            float vy = (float)y + (float)(iy - 2) + dy;
            float x0f = floorf(vx), y0f = floorf(vy);
            float fx = vx - x0f, fy = vy - y0f;
            float wx[2] = {1.f - fx, fx};
            float wy[2] = {1.f - fy, fy};
            #pragma unroll
            for (int cy = 0; cy < 2; ++cy) {
                #pragma unroll
                for (int cx = 0; cx < 2; ++cx) {
                    float xf = x0f + (float)cx;
                    float yf = y0f + (float)cy;
                    bool valid = (xf >= 0.f) & (xf <= 127.f) & (yf >= 0.f) & (yf <= 127.f);
                    int xi = min(max((int)xf, 0), 127);
                    int yi = min(max((int)yf, 0), 127);
                    s_off[pi][g][cy * 2 + cx] = (yi * W + xi) * 1024;
                    s_w[pi][g][cy * 2 + cx] = valid ? wx[cx] * wy[cy] : 0.f;
                }
            }
        }
        __syncthreads();

        float4 q4 = *(const float4*)(q_t + (size_t)pix * C + 4 * g);
        q4.x *= 0.25f; q4.y *= 0.25f; q4.z *= 0.25f; q4.w *= 0.25f;

        float m = -1e30f;
        float sum = 0.f;
        float4 oc = {0.f, 0.f, 0.f, 0.f};

        #pragma unroll 1
        for (int p = 0; p < 25; ++p) {
            int4   off = *(const int4*)&s_off[pi][p][0];
            float4 w   = *(const float4*)&s_w[pi][p][0];
            const char* a0 = kvb + off.x + go;
            const char* a1 = kvb + off.y + go;
            const char* a2 = kvb + off.z + go;
            const char* a3 = kvb + off.w + go;

            float4 k0 = *(const float4*)(a0);
            float4 k1 = *(const float4*)(a1);
            float4 k2 = *(const float4*)(a2);
            float4 k3 = *(const float4*)(a3);
            float4 ks;
            ks.x = w.x * k0.x + w.y * k1.x + w.z * k2.x + w.w * k3.x;
            ks.y = w.x * k0.y + w.y * k1.y + w.z * k2.y + w.w * k3.y;
            ks.z = w.x * k0.z + w.y * k1.z + w.z * k2.z + w.w * k3.z;
            ks.w = w.x * k0.w + w.y * k1.w + w.z * k2.w + w.w * k3.w;
            float sp = q4.x * ks.x + q4.y * ks.y + q4.z * ks.z + q4.w * ks.w;
            sp += __shfl_xor(sp, 1);
            sp += __shfl_xor(sp, 2);

            float4 v0 = *(const float4*)(a0 + 512);
            float4 v1 = *(const float4*)(a1 + 512);
            float4 v2 = *(const float4*)(a2 + 512);
            float4 v3 = *(const float4*)(a3 + 512);
            float4 vs;
            vs.x = w.x * v0.x + w.y * v1.x + w.z * v2.x + w.w * v3.x;
            vs.y = w.x * v0.y + w.y * v1.y + w.z * v2.y + w.w * v3.y;
            vs.z = w.x * v0.z + w.y * v1.z + w.z * v2.z + w.w * v3.z;
            vs.w = w.x * v0.w + w.y * v1.w + w.z * v2.w + w.w * v3.w;

            float mn   = fmaxf(m, sp);
            float corr = __expf(m - mn);
            float e    = __expf(sp - mn);
            sum  = sum * corr + e;
            oc.x = oc.x * corr + e * vs.x;
            oc.y = oc.y * corr + e * vs.y;
            oc.z = oc.z * corr + e * vs.z;
            oc.w = oc.w * corr + e * vs.w;
            m = mn;
        }

        float inv = 1.f / sum;
        ushort4 ob;
        ob.x = f2bf(oc.x * inv);
        ob.y = f2bf(oc.y * inv);
        ob.z = f2bf(oc.z * inv);
        ob.w = f2bf(oc.w * inv);
        *(ushort4*)(ao_t + (size_t)pix * C + 4 * g) = ob;
    }
}

// ---------------- kernel 4: fc + MLP + residual + stats via MFMA, LDS-staged weights ----------------
// 512 blocks x 256 thr; 32 px/block. Phases: wfc -> G1; w1 (2 M-halves) -> G2;
// w2 (2 M-halves) -> G3. Residual read back from l1 (bf16).
__global__ __launch_bounds__(256, 2)
void mlp_mfma(const unsigned short* __restrict__ ao_t, const unsigned short* __restrict__ wb,
              const float* __restrict__ b1, const float* __restrict__ b2,
              float* __restrict__ out2, float* __restrict__ accum) {
    __shared__ unsigned short wbuf[16384];    // 32 KB weight panel
    __shared__ unsigned short l1[32 * 128];   // out1 bf16 (pixel-swizzled)
    __shared__ unsigned short lh[32 * 256];   // hid  bf16 (pixel-swizzled)
    const int t = threadIdx.x;
    const int p0 = blockIdx.x * 32;
    const int lane = t & 63, row16 = lane & 15, g = lane >> 4;
    const int w = t >> 6, nh = w & 1, mh = w >> 1;
    const int ploc = nh * 16 + row16;
    const int pix = p0 + ploc;
    const int swz = (ploc & 7) << 3;
    const unsigned short* wfc_b = wb + 49152;
    const unsigned short* w1_b  = wb + 65536;
    const unsigned short* w2_b  = wb + 98304;

    // B-fragments for GEMM1 from global; issued first so latency hides under staging
    short8v bf[4];
    #pragma unroll
    for (int kk = 0; kk < 4; ++kk)
        bf[kk] = *(const short8v*)&ao_t[(size_t)pix * 128 + kk * 32 + g * 8];

    stage32<4>(wfc_b, wbuf, t);
    __syncthreads();

    // GEMM1: out1 = wfc . ao
    {
        f32x4 acc1[4] = {};
        #pragma unroll
        for (int kk = 0; kk < 4; ++kk) {
            #pragma unroll
            for (int f = 0; f < 4; ++f) {
                int row = mh * 64 + f * 16 + row16;
                short8v a = *(const short8v*)&wbuf[(row << 7) + (((kk * 4 + g) ^ (row & 7)) << 3)];
                acc1[f] = __builtin_amdgcn_mfma_f32_16x16x32_bf16(a, bf[kk], acc1[f], 0, 0, 0);
            }
        }
        #pragma unroll
        for (int f = 0; f < 4; ++f)
            #pragma unroll
            for (int r = 0; r < 4; ++r) {
                int o = mh * 64 + f * 16 + g * 4 + r;
                l1[ploc * 128 + (o ^ swz)] = f2bf(acc1[f][r]);
            }
    }
    __syncthreads();

    // GEMM2: hid = leaky(w1 . out1 + b1), two M-halves of 128 rows
    #pragma unroll 1
    for (int s = 0; s < 2; ++s) {
        stage32<4>(w1_b + s * 16384, wbuf, t);
        __syncthreads();
        f32x4 acc2[4] = {};
        #pragma unroll
        for (int kk = 0; kk < 4; ++kk) {
            short8v b = *(const short8v*)&l1[ploc * 128 + ((kk * 32 + g * 8) ^ swz)];
            #pragma unroll
            for (int f = 0; f < 4; ++f) {
                int row = mh * 64 + f * 16 + row16;
                short8v a = *(const short8v*)&wbuf[(row << 7) + (((kk * 4 + g) ^ (row & 7)) << 3)];
                acc2[f] = __builtin_amdgcn_mfma_f32_16x16x32_bf16(a, b, acc2[f], 0, 0, 0);
            }
        }
        #pragma unroll
        for (int f = 0; f < 4; ++f) {
            int h = s * 128 + mh * 64 + f * 16 + g * 4;
            float4 bb = *(const float4*)&b1[h];
            float hv[4] = {acc2[f][0] + bb.x, acc2[f][1] + bb.y,
                           acc2[f][2] + bb.z, acc2[f][3] + bb.w};
            #pragma unroll
            for (int r = 0; r < 4; ++r) {
                float v = (hv[r] >= 0.f) ? hv[r] : 0.2f * hv[r];
                lh[ploc * 256 + ((h + r) ^ swz)] = f2bf(v);
            }
        }
        __syncthreads();
    }

    // GEMM3: out2 = w2 . hid + b2 + out1, two M-halves of 64 rows
    float lsum = 0.f, lsq = 0.f;
    #pragma unroll 1
    for (int s = 0; s < 2; ++s) {
        stage32<5>(w2_b + s * 16384, wbuf, t);
        __syncthreads();
        f32x4 acc3[2] = {};
        #pragma unroll
        for (int kk = 0; kk < 8; ++kk) {
            short8v b = *(const short8v*)&lh[ploc * 256 + ((kk * 32 + g * 8) ^ swz)];
            #pragma unroll
            for (int f = 0; f < 2; ++f) {
                int row = mh * 32 + f * 16 + row16;           // local row in [0,64)
                short8v a = *(const short8v*)&wbuf[(row << 8) + (((kk * 4 + g) ^ (row & 7)) << 3)];
                acc3[f] = __builtin_amdgcn_mfma_f32_16x16x32_bf16(a, b, acc3[f], 0, 0, 0);
            }
        }
        #pragma unroll
        for (int f = 0; f < 2; ++f) {
            int ob = s * 64 + mh * 32 + f * 16 + g * 4;
            float4 b2v = *(const float4*)&b2[ob];
            ushort4 res = *(const ushort4*)&l1[ploc * 128 + (ob ^ swz)];
            float bv[4] = {b2v.x, b2v.y, b2v.z, b2v.w};
            unsigned short rr[4] = {res.x, res.y, res.z, res.w};
            #pragma unroll
            for (int r = 0; r < 4; ++r) {
                float v = acc3[f][r] + bf2f(rr[r]) + bv[r];
                out2[(size_t)(ob + r) * HW + pix] = v;
                lsum += v;
                lsq += v * v;
            }
        }
        __syncthreads();
    }

    #pragma unroll
    for (int s = 1; s < 64; s <<= 1) {
        lsum += __shfl_xor(lsum, s);
        lsq  += __shfl_xor(lsq, s);
    }
    if (lane == 0) {
        atomicAdd(&accum[0], lsum);
        atomicAdd(&accum[1], lsq);
    }
}

// ---------------- kernel 5: global layernorm (in place on d_out) ----------------
__global__ void norm_kernel(float* __restrict__ out2, const float* __restrict__ accum,
                            const float* __restrict__ gn_w, const float* __restrict__ gn_b) {
    const int gid = blockIdx.x * 256 + threadIdx.x;
    const float invN = 1.f / 2097152.f;
    float mean = accum[0] * invN;
    float var = accum[1] * invN - mean * mean;
    float rstd = rsqrtf(var + 1e-5f);
    int base = gid * 4;
    int o = base >> 14;
    float g = gn_w[o] * rstd;
    float b = gn_b[o];
    float4 v = *(const float4*)(out2 + base);
    float4 r;
    r.x = (v.x - mean) * g + b;
    r.y = (v.y - mean) * g + b;
    r.z = (v.z - mean) * g + b;
    r.w = (v.w - mean) * g + b;
    *(float4*)(out2 + base) = r;
}

extern "C" void kernel_launch(void* const* d_in, const int* in_sizes, int n_in,
                              void* d_out, int out_size, void* d_ws, size_t ws_size,
                              hipStream_t stream) {
    const float* query  = (const float*)d_in[0];
    const float* key    = (const float*)d_in[1];
    const float* value  = (const float*)d_in[2];
    const float* deform = (const float*)d_in[3];
    const float* w_q    = (const float*)d_in[4];
    const float* w_k    = (const float*)d_in[5];
    const float* w_v    = (const float*)d_in[6];
    const float* w_fc   = (const float*)d_in[7];
    const float* mlp_w1 = (const float*)d_in[8];
    const float* mlp_b1 = (const float*)d_in[9];
    const float* mlp_w2 = (const float*)d_in[10];
    const float* mlp_b2 = (const float*)d_in[11];
    const float* gn_w   = (const float*)d_in[12];
    const float* gn_b   = (const float*)d_in[13];

    float* out = (float*)d_out;
    char* wsb  = (char*)d_ws;

    // ws layout (bytes): q_t f32 [0,8M) | kv_t f32 [8M,24M) | ao bf16 [24M,28M)
    //                    | wb bf16 [28M, 28M+256K) | acc [29M, +8)
    float* q_t = (float*)wsb;
    float* kv_t = (float*)(wsb + ((size_t)8 << 20));
    unsigned short* ao_t = (unsigned short*)(wsb + ((size_t)24 << 20));
    unsigned short* wb = (unsigned short*)(wsb + ((size_t)28 << 20));
    float* acc = (float*)(wsb + ((size_t)29 << 20));

    zero_acc_kernel<<<1, 1, 0, stream>>>(acc);
    prep_weights<<<512, 256, 0, stream>>>(w_q, w_k, w_v, w_fc, mlp_w1, mlp_w2, wb);
    qkv_mfma<<<512, 256, 0, stream>>>(query, key, value, wb, q_t, kv_t);
    attn_kernel<<<1024, 256, 0, stream>>>(q_t, kv_t, deform, ao_t);
    mlp_mfma<<<512, 256, 0, stream>>>(ao_t, wb, mlp_b1, mlp_b2, out, acc);
    norm_kernel<<<2048, 256, 0, stream>>>(out, acc, gn_w, gn_b);
}

// Round 8
// 133.622 us; speedup vs baseline: 4.9410x; 1.0935x over previous
//
#include <hip/hip_runtime.h>
#include <hip/hip_bf16.h>

#define HW 16384
#define W 128
#define C 128
#define HID 256

typedef __attribute__((ext_vector_type(8))) short short8v;
typedef __attribute__((ext_vector_type(4))) float f32x4;

__device__ __forceinline__ unsigned short f2bf(float f) {
    union { float f; unsigned u; } x; x.f = f;
    unsigned r = x.u + 0x7FFF + ((x.u >> 16) & 1);
    return (unsigned short)(r >> 16);
}
__device__ __forceinline__ float bf2f(unsigned short b) {
    union { unsigned u; float f; } x; x.u = ((unsigned)b) << 16;
    return x.f;
}

// Stage a 32KB weight panel (2048 granules of 16B) global->LDS.
// Linear coalesced global read; swizzled LDS write: granule col ^= (row&7).
// RSH = log2(granules per row): 4 for K=128 rows, 5 for K=256 rows.
template<int RSH>
__device__ __forceinline__ void stage32(const unsigned short* __restrict__ src,
                                        unsigned short* lds, int t) {
    #pragma unroll
    for (int c = 0; c < 8; ++c) {
        int gi = c * 256 + t;
        int row = gi >> RSH, colg = gi & ((1 << RSH) - 1);
        short8v v = *(const short8v*)(src + (size_t)gi * 8);
        *(short8v*)(lds + (size_t)(((row << RSH) + (colg ^ (row & 7))) << 3)) = v;
    }
}

// ---------------- kernel 0: zero the stat accumulators ----------------
__global__ void zero_acc_kernel(float* acc) {
    acc[0] = 0.f;
    acc[1] = 0.f;
}

// ---------------- kernel 1: convert all weights to bf16 ----------------
// layout in wb: wq[16384] wk[16384] wv[16384] wfc[16384] w1[32768] w2[32768]
__global__ void prep_weights(const float* __restrict__ wq, const float* __restrict__ wk,
                             const float* __restrict__ wv, const float* __restrict__ wfc,
                             const float* __restrict__ w1, const float* __restrict__ w2,
                             unsigned short* __restrict__ wb) {
    int i = blockIdx.x * 256 + threadIdx.x;   // 0..131071
    float v;
    if (i < 16384)       v = wq[i];
    else if (i < 32768)  v = wk[i - 16384];
    else if (i < 49152)  v = wv[i - 32768];
    else if (i < 65536)  v = wfc[i - 49152];
    else if (i < 98304)  v = w1[i - 65536];
    else                 v = w2[i - 98304];
    wb[i] = f2bf(v);
}

// ---------------- kernel 2: q/k/v 1x1 convs via MFMA, LDS-staged weights ----------------
__global__ __launch_bounds__(256, 2)
void qkv_mfma(const float* __restrict__ q_in, const float* __restrict__ k_in,
              const float* __restrict__ v_in, const unsigned short* __restrict__ wb,
              float* __restrict__ q_t, float* __restrict__ kv_t) {
    __shared__ unsigned short lx[3][32 * 128];   // 24 KB inputs (pixel-swizzled)
    __shared__ unsigned short wbuf[16384];       // 32 KB weight panel
    const int t = threadIdx.x;
    const int p0 = blockIdx.x * 32;
    const int lane = t & 63, row16 = lane & 15, g = lane >> 4;
    const int w = t >> 6, nh = w & 1, mh = w >> 1;
    const int ploc = nh * 16 + row16;
    const int pix = p0 + ploc;
    const int swz = (ploc & 7) << 3;

    stage32<4>(wb, wbuf, t);    // wq, in flight during x-tile conversion

    const float* ins[3] = {q_in, k_in, v_in};
    #pragma unroll
    for (int m = 0; m < 3; ++m) {
        #pragma unroll
        for (int it = 0; it < 16; ++it) {
            int e = t + 256 * it;          // 0..4095
            int p = e & 31, c = e >> 5;
            lx[m][p * 128 + (c ^ ((p & 7) << 3))] = f2bf(ins[m][c * HW + p0 + p]);
        }
    }

    #pragma unroll 1
    for (int m = 0; m < 3; ++m) {
        if (m > 0) {
            __syncthreads();               // previous GEMM done reading wbuf
            stage32<4>(wb + m * 16384, wbuf, t);
        }
        __syncthreads();                   // staging (and lx on m=0) visible

        f32x4 acc[4] = {};
        #pragma unroll
        for (int kk = 0; kk < 4; ++kk) {
            short8v b = *(const short8v*)&lx[m][ploc * 128 + ((kk * 32 + g * 8) ^ swz)];
            #pragma unroll
            for (int f = 0; f < 4; ++f) {
                int row = mh * 64 + f * 16 + row16;
                short8v a = *(const short8v*)&wbuf[(row << 7) + (((kk * 4 + g) ^ (row & 7)) << 3)];
                acc[f] = __builtin_amdgcn_mfma_f32_16x16x32_bf16(a, b, acc[f], 0, 0, 0);
            }
        }
        #pragma unroll
        for (int f = 0; f < 4; ++f) {
            int o = mh * 64 + f * 16 + g * 4;
            float4 st = make_float4(acc[f][0], acc[f][1], acc[f][2], acc[f][3]);
            if (m == 0)      *(float4*)&q_t[(size_t)pix * 128 + o] = st;
            else if (m == 1) *(float4*)&kv_t[(size_t)pix * 256 + o] = st;
            else             *(float4*)&kv_t[(size_t)pix * 256 + 128 + o] = st;
        }
    }
}

// ---------------- kernel 3: deformable attention, factorized 6x6 corner grid ----------------
// All 25 taps share (fx,fy): corners form a 6x6 integer grid. Phase A: 36 partial
// dots d[]; scores = 4-FMA bilinear combine + head shfl-reduce; softmax in regs;
// corner weights b[] = transpose-bilinear of attn probs; Phase B: 36 V-loads.
// 1024 blocks x 256 thr, 2 passes, 8 px/block, 32 thr/px, 4 ch/thr. No LDS.
__global__ __launch_bounds__(256, 2)
void attn_kernel(const float* __restrict__ q_t, const float* __restrict__ kv_t,
                 const float* __restrict__ deform, unsigned short* __restrict__ ao_t) {
    const int t = threadIdx.x;
    const int pi = t >> 5;
    const int g = t & 31;
    const char* kvb = (const char*)kv_t;
    const int go = g * 16;

    #pragma unroll 1
    for (int pass = 0; pass < 2; ++pass) {
        const int jj = blockIdx.x + pass * 1024;
        const int y = jj >> 4;
        const int x = ((jj & 15) << 3) + pi;
        const int pix = y * W + x;

        const float dx = deform[pix];
        const float dy = deform[HW + pix];
        const float fdx = floorf(dx), fdy = floorf(dy);
        const float fx = dx - fdx, fy = dy - fdy;
        const float wx0 = 1.f - fx, wx1 = fx, wy0 = 1.f - fy, wy1 = fy;
        const int x0 = x - 2 + (int)fdx;
        const int y0 = y - 2 + (int)fdy;

        int   coff[6], roff[6];
        float colv[6], rowv[6];
        #pragma unroll
        for (int j = 0; j < 6; ++j) {
            int xc = x0 + j, yc = y0 + j;
            colv[j] = ((unsigned)xc <= 127u) ? 1.f : 0.f;
            rowv[j] = ((unsigned)yc <= 127u) ? 1.f : 0.f;
            coff[j] = (min(max(xc, 0), 127) << 10) + go;   // x*1KB + channel byte off
            roff[j] = min(max(yc, 0), 127) << 17;          // y*128KB
        }

        float4 q4 = *(const float4*)(q_t + (size_t)pix * C + 4 * g);
        q4.x *= 0.25f; q4.y *= 0.25f; q4.z *= 0.25f; q4.w *= 0.25f;   // 1/sqrt(16)

        // ---- phase A: 36 per-thread partial dots ----
        float d[36];
        #pragma unroll
        for (int jy = 0; jy < 6; ++jy) {
            #pragma unroll
            for (int jx = 0; jx < 6; ++jx) {
                float4 k = *(const float4*)(kvb + (roff[jy] + coff[jx]));
                float dd = q4.x * k.x + q4.y * k.y + q4.z * k.z + q4.w * k.w;
                d[jy * 6 + jx] = dd * (rowv[jy] * colv[jx]);
            }
        }

        // ---- scores: bilinear combine + head reduce (4 lanes/head) ----
        float s[25];
        #pragma unroll
        for (int iy = 0; iy < 5; ++iy) {
            #pragma unroll
            for (int ix = 0; ix < 5; ++ix) {
                float sp = wy0 * (wx0 * d[iy * 6 + ix]       + wx1 * d[iy * 6 + ix + 1])
                         + wy1 * (wx0 * d[(iy + 1) * 6 + ix] + wx1 * d[(iy + 1) * 6 + ix + 1]);
                sp += __shfl_xor(sp, 1);
                sp += __shfl_xor(sp, 2);
                s[iy * 5 + ix] = sp;
            }
        }

        // ---- softmax over 25 (in registers; identical in all 4 head lanes) ----
        float m = s[0];
        #pragma unroll
        for (int p = 1; p < 25; ++p) m = fmaxf(m, s[p]);
        float sum = 0.f;
        #pragma unroll
        for (int p = 0; p < 25; ++p) {
            float e = __expf(s[p] - m);
            s[p] = e;
            sum += e;
        }
        const float inv = 1.f / sum;

        // ---- corner weights: transpose bilinear of probs, fold validity ----
        float b[36];
        #pragma unroll
        for (int jy = 0; jy < 6; ++jy) {
            #pragma unroll
            for (int jx = 0; jx < 6; ++jx) {
                float acc = 0.f;
                if (jy < 5  && jx < 5)  acc += wy0 * wx0 * s[jy * 5 + jx];
                if (jy < 5  && jx >= 1) acc += wy0 * wx1 * s[jy * 5 + jx - 1];
                if (jy >= 1 && jx < 5)  acc += wy1 * wx0 * s[(jy - 1) * 5 + jx];
                if (jy >= 1 && jx >= 1) acc += wy1 * wx1 * s[(jy - 1) * 5 + jx - 1];
                b[jy * 6 + jx] = acc * (rowv[jy] * colv[jx]);
            }
        }

        // ---- phase B: 36 V gathers ----
        float4 oc = {0.f, 0.f, 0.f, 0.f};
        #pragma unroll
        for (int jy = 0; jy < 6; ++jy) {
            #pragma unroll
            for (int jx = 0; jx < 6; ++jx) {
                float4 v = *(const float4*)(kvb + (roff[jy] + coff[jx]) + 512);
                float bw = b[jy * 6 + jx];
                oc.x += bw * v.x;
                oc.y += bw * v.y;
                oc.z += bw * v.z;
                oc.w += bw * v.w;
            }
        }

        ushort4 ob;
        ob.x = f2bf(oc.x * inv);
        ob.y = f2bf(oc.y * inv);
        ob.z = f2bf(oc.z * inv);
        ob.w = f2bf(oc.w * inv);
        *(ushort4*)(ao_t + (size_t)pix * C + 4 * g) = ob;
    }
}

// ---------------- kernel 4: fc + MLP + residual + stats via MFMA, LDS-staged weights ----------------
__global__ __launch_bounds__(256, 2)
void mlp_mfma(const unsigned short* __restrict__ ao_t, const unsigned short* __restrict__ wb,
              const float* __restrict__ b1, const float* __restrict__ b2,
              float* __restrict__ out2, float* __restrict__ accum) {
    __shared__ unsigned short wbuf[16384];    // 32 KB weight panel
    __shared__ unsigned short l1[32 * 128];   // out1 bf16 (pixel-swizzled)
    __shared__ unsigned short lh[32 * 256];   // hid  bf16 (pixel-swizzled)
    const int t = threadIdx.x;
    const int p0 = blockIdx.x * 32;
    const int lane = t & 63, row16 = lane & 15, g = lane >> 4;
    const int w = t >> 6, nh = w & 1, mh = w >> 1;
    const int ploc = nh * 16 + row16;
    const int pix = p0 + ploc;
    const int swz = (ploc & 7) << 3;
    const unsigned short* wfc_b = wb + 49152;
    const unsigned short* w1_b  = wb + 65536;
    const unsigned short* w2_b  = wb + 98304;

    short8v bf[4];
    #pragma unroll
    for (int kk = 0; kk < 4; ++kk)
        bf[kk] = *(const short8v*)&ao_t[(size_t)pix * 128 + kk * 32 + g * 8];

    stage32<4>(wfc_b, wbuf, t);
    __syncthreads();

    // GEMM1: out1 = wfc . ao
    {
        f32x4 acc1[4] = {};
        #pragma unroll
        for (int kk = 0; kk < 4; ++kk) {
            #pragma unroll
            for (int f = 0; f < 4; ++f) {
                int row = mh * 64 + f * 16 + row16;
                short8v a = *(const short8v*)&wbuf[(row << 7) + (((kk * 4 + g) ^ (row & 7)) << 3)];
                acc1[f] = __builtin_amdgcn_mfma_f32_16x16x32_bf16(a, bf[kk], acc1[f], 0, 0, 0);
            }
        }
        #pragma unroll
        for (int f = 0; f < 4; ++f)
            #pragma unroll
            for (int r = 0; r < 4; ++r) {
                int o = mh * 64 + f * 16 + g * 4 + r;
                l1[ploc * 128 + (o ^ swz)] = f2bf(acc1[f][r]);
            }
    }
    __syncthreads();

    // GEMM2: hid = leaky(w1 . out1 + b1), two M-halves of 128 rows
    #pragma unroll 1
    for (int s = 0; s < 2; ++s) {
        stage32<4>(w1_b + s * 16384, wbuf, t);
        __syncthreads();
        f32x4 acc2[4] = {};
        #pragma unroll
        for (int kk = 0; kk < 4; ++kk) {
            short8v b = *(const short8v*)&l1[ploc * 128 + ((kk * 32 + g * 8) ^ swz)];
            #pragma unroll
            for (int f = 0; f < 4; ++f) {
                int row = mh * 64 + f * 16 + row16;
                short8v a = *(const short8v*)&wbuf[(row << 7) + (((kk * 4 + g) ^ (row & 7)) << 3)];
                acc2[f] = __builtin_amdgcn_mfma_f32_16x16x32_bf16(a, b, acc2[f], 0, 0, 0);
            }
        }
        #pragma unroll
        for (int f = 0; f < 4; ++f) {
            int h = s * 128 + mh * 64 + f * 16 + g * 4;
            float4 bb = *(const float4*)&b1[h];
            float hv[4] = {acc2[f][0] + bb.x, acc2[f][1] + bb.y,
                           acc2[f][2] + bb.z, acc2[f][3] + bb.w};
            #pragma unroll
            for (int r = 0; r < 4; ++r) {
                float v = (hv[r] >= 0.f) ? hv[r] : 0.2f * hv[r];
                lh[ploc * 256 + ((h + r) ^ swz)] = f2bf(v);
            }
        }
        __syncthreads();
    }

    // GEMM3: out2 = w2 . hid + b2 + out1, two M-halves of 64 rows
    float lsum = 0.f, lsq = 0.f;
    #pragma unroll 1
    for (int s = 0; s < 2; ++s) {
        stage32<5>(w2_b + s * 16384, wbuf, t);
        __syncthreads();
        f32x4 acc3[2] = {};
        #pragma unroll
        for (int kk = 0; kk < 8; ++kk) {
            short8v b = *(const short8v*)&lh[ploc * 256 + ((kk * 32 + g * 8) ^ swz)];
            #pragma unroll
            for (int f = 0; f < 2; ++f) {
                int row = mh * 32 + f * 16 + row16;           // local row in [0,64)
                short8v a = *(const short8v*)&wbuf[(row << 8) + (((kk * 4 + g) ^ (row & 7)) << 3)];
                acc3[f] = __builtin_amdgcn_mfma_f32_16x16x32_bf16(a, b, acc3[f], 0, 0, 0);
            }
        }
        #pragma unroll
        for (int f = 0; f < 2; ++f) {
            int ob = s * 64 + mh * 32 + f * 16 + g * 4;
            float4 b2v = *(const float4*)&b2[ob];
            ushort4 res = *(const ushort4*)&l1[ploc * 128 + (ob ^ swz)];
            float bv[4] = {b2v.x, b2v.y, b2v.z, b2v.w};
            unsigned short rr[4] = {res.x, res.y, res.z, res.w};
            #pragma unroll
            for (int r = 0; r < 4; ++r) {
                float v = acc3[f][r] + bf2f(rr[r]) + bv[r];
                out2[(size_t)(ob + r) * HW + pix] = v;
                lsum += v;
                lsq += v * v;
            }
        }
        __syncthreads();
    }

    #pragma unroll
    for (int s = 1; s < 64; s <<= 1) {
        lsum += __shfl_xor(lsum, s);
        lsq  += __shfl_xor(lsq, s);
    }
    if (lane == 0) {
        atomicAdd(&accum[0], lsum);
        atomicAdd(&accum[1], lsq);
    }
}

// ---------------- kernel 5: global layernorm (in place on d_out) ----------------
__global__ void norm_kernel(float* __restrict__ out2, const float* __restrict__ accum,
                            const float* __restrict__ gn_w, const float* __restrict__ gn_b) {
    const int gid = blockIdx.x * 256 + threadIdx.x;
    const float invN = 1.f / 2097152.f;
    float mean = accum[0] * invN;
    float var = accum[1] * invN - mean * mean;
    float rstd = rsqrtf(var + 1e-5f);
    int base = gid * 4;
    int o = base >> 14;
    float g = gn_w[o] * rstd;
    float b = gn_b[o];
    float4 v = *(const float4*)(out2 + base);
    float4 r;
    r.x = (v.x - mean) * g + b;
    r.y = (v.y - mean) * g + b;
    r.z = (v.z - mean) * g + b;
    r.w = (v.w - mean) * g + b;
    *(float4*)(out2 + base) = r;
}

extern "C" void kernel_launch(void* const* d_in, const int* in_sizes, int n_in,
                              void* d_out, int out_size, void* d_ws, size_t ws_size,
                              hipStream_t stream) {
    const float* query  = (const float*)d_in[0];
    const float* key    = (const float*)d_in[1];
    const float* value  = (const float*)d_in[2];
    const float* deform = (const float*)d_in[3];
    const float* w_q    = (const float*)d_in[4];
    const float* w_k    = (const float*)d_in[5];
    const float* w_v    = (const float*)d_in[6];
    const float* w_fc   = (const float*)d_in[7];
    const float* mlp_w1 = (const float*)d_in[8];
    const float* mlp_b1 = (const float*)d_in[9];
    const float* mlp_w2 = (const float*)d_in[10];
    const float* mlp_b2 = (const float*)d_in[11];
    const float* gn_w   = (const float*)d_in[12];
    const float* gn_b   = (const float*)d_in[13];

    float* out = (float*)d_out;
    char* wsb  = (char*)d_ws;

    // ws layout (bytes): q_t f32 [0,8M) | kv_t f32 [8M,24M) | ao bf16 [24M,28M)
    //                    | wb bf16 [28M, 28M+256K) | acc [29M, +8)
    float* q_t = (float*)wsb;
    float* kv_t = (float*)(wsb + ((size_t)8 << 20));
    unsigned short* ao_t = (unsigned short*)(wsb + ((size_t)24 << 20));
    unsigned short* wb = (unsigned short*)(wsb + ((size_t)28 << 20));
    float* acc = (float*)(wsb + ((size_t)29 << 20));

    zero_acc_kernel<<<1, 1, 0, stream>>>(acc);
    prep_weights<<<512, 256, 0, stream>>>(w_q, w_k, w_v, w_fc, mlp_w1, mlp_w2, wb);
    qkv_mfma<<<512, 256, 0, stream>>>(query, key, value, wb, q_t, kv_t);
    attn_kernel<<<1024, 256, 0, stream>>>(q_t, kv_t, deform, ao_t);
    mlp_mfma<<<512, 256, 0, stream>>>(ao_t, wb, mlp_b1, mlp_b2, out, acc);
    norm_kernel<<<2048, 256, 0, stream>>>(out, acc, gn_w, gn_b);
}

// Round 9
// 81.982 us; speedup vs baseline: 8.0533x; 1.6299x over previous
//
#include <hip/hip_runtime.h>
#include <hip/hip_bf16.h>

#define HW 16384
#define W 128
#define C 128
#define HID 256

typedef __attribute__((ext_vector_type(8))) short short8v;
typedef __attribute__((ext_vector_type(4))) float f32x4;

__device__ __forceinline__ unsigned short f2bf(float f) {
    union { float f; unsigned u; } x; x.f = f;
    unsigned r = x.u + 0x7FFF + ((x.u >> 16) & 1);
    return (unsigned short)(r >> 16);
}
__device__ __forceinline__ float bf2f(unsigned short b) {
    union { unsigned u; float f; } x; x.u = ((unsigned)b) << 16;
    return x.f;
}

// ---- async-stage split: issue 32KB panel (8 x 16B per thread) into regs ----
__device__ __forceinline__ void stage_load(const unsigned short* __restrict__ src,
                                           short8v* r, int t) {
    #pragma unroll
    for (int c = 0; c < 8; ++c)
        r[c] = *(const short8v*)(src + (size_t)(c * 256 + t) * 8);
}
// ---- commit regs to LDS, XOR-swizzled: granule col ^= (row&7). RSH=log2(granules/row)
template<int RSH>
__device__ __forceinline__ void stage_write(const short8v* r, unsigned short* lds, int t) {
    #pragma unroll
    for (int c = 0; c < 8; ++c) {
        int gi = c * 256 + t;
        int row = gi >> RSH, colg = gi & ((1 << RSH) - 1);
        *(short8v*)(lds + (size_t)(((row << RSH) + (colg ^ (row & 7))) << 3)) = r[c];
    }
}
template<int RSH>
__device__ __forceinline__ void stage32(const unsigned short* __restrict__ src,
                                        unsigned short* lds, int t) {
    #pragma unroll
    for (int c = 0; c < 8; ++c) {
        int gi = c * 256 + t;
        int row = gi >> RSH, colg = gi & ((1 << RSH) - 1);
        short8v v = *(const short8v*)(src + (size_t)gi * 8);
        *(short8v*)(lds + (size_t)(((row << RSH) + (colg ^ (row & 7))) << 3)) = v;
    }
}

// ---------------- kernel 1: convert all weights to bf16 ----------------
// layout in wb: wq[16384] wk[16384] wv[16384] wfc[16384] w1[32768] w2[32768]
__global__ void prep_weights(const float* __restrict__ wq, const float* __restrict__ wk,
                             const float* __restrict__ wv, const float* __restrict__ wfc,
                             const float* __restrict__ w1, const float* __restrict__ w2,
                             unsigned short* __restrict__ wb) {
    int i = blockIdx.x * 256 + threadIdx.x;   // 0..131071
    float v;
    if (i < 16384)       v = wq[i];
    else if (i < 32768)  v = wk[i - 16384];
    else if (i < 49152)  v = wv[i - 32768];
    else if (i < 65536)  v = wfc[i - 49152];
    else if (i < 98304)  v = w1[i - 65536];
    else                 v = w2[i - 98304];
    wb[i] = f2bf(v);
}

// ---------------- kernel 2: q/k/v 1x1 convs via MFMA, LDS-staged weights ----------------
__global__ __launch_bounds__(256, 2)
void qkv_mfma(const float* __restrict__ q_in, const float* __restrict__ k_in,
              const float* __restrict__ v_in, const unsigned short* __restrict__ wb,
              float* __restrict__ q_t, float* __restrict__ kv_t) {
    __shared__ unsigned short lx[3][32 * 128];   // 24 KB inputs (pixel-swizzled)
    __shared__ unsigned short wbuf[16384];       // 32 KB weight panel
    const int t = threadIdx.x;
    const int p0 = blockIdx.x * 32;
    const int lane = t & 63, row16 = lane & 15, g = lane >> 4;
    const int w = t >> 6, nh = w & 1, mh = w >> 1;
    const int ploc = nh * 16 + row16;
    const int pix = p0 + ploc;
    const int swz = (ploc & 7) << 3;

    stage32<4>(wb, wbuf, t);    // wq, in flight during x-tile conversion

    const float* ins[3] = {q_in, k_in, v_in};
    #pragma unroll
    for (int m = 0; m < 3; ++m) {
        #pragma unroll
        for (int it = 0; it < 16; ++it) {
            int e = t + 256 * it;          // 0..4095
            int p = e & 31, c = e >> 5;
            lx[m][p * 128 + (c ^ ((p & 7) << 3))] = f2bf(ins[m][c * HW + p0 + p]);
        }
    }

    #pragma unroll 1
    for (int m = 0; m < 3; ++m) {
        if (m > 0) {
            __syncthreads();               // previous GEMM done reading wbuf
            stage32<4>(wb + m * 16384, wbuf, t);
        }
        __syncthreads();                   // staging (and lx on m=0) visible

        f32x4 acc[4] = {};
        #pragma unroll
        for (int kk = 0; kk < 4; ++kk) {
            short8v b = *(const short8v*)&lx[m][ploc * 128 + ((kk * 32 + g * 8) ^ swz)];
            #pragma unroll
            for (int f = 0; f < 4; ++f) {
                int row = mh * 64 + f * 16 + row16;
                short8v a = *(const short8v*)&wbuf[(row << 7) + (((kk * 4 + g) ^ (row & 7)) << 3)];
                acc[f] = __builtin_amdgcn_mfma_f32_16x16x32_bf16(a, b, acc[f], 0, 0, 0);
            }
        }
        #pragma unroll
        for (int f = 0; f < 4; ++f) {
            int o = mh * 64 + f * 16 + g * 4;
            float4 st = make_float4(acc[f][0], acc[f][1], acc[f][2], acc[f][3]);
            if (m == 0)      *(float4*)&q_t[(size_t)pix * 128 + o] = st;
            else if (m == 1) *(float4*)&kv_t[(size_t)pix * 256 + o] = st;
            else             *(float4*)&kv_t[(size_t)pix * 256 + 128 + o] = st;
        }
    }
}

// ---------------- kernel 3: deformable attention, factorized 6x6 corner grid ----------------
__global__ __launch_bounds__(256, 2)
void attn_kernel(const float* __restrict__ q_t, const float* __restrict__ kv_t,
                 const float* __restrict__ deform, unsigned short* __restrict__ ao_t) {
    const int t = threadIdx.x;
    const int pi = t >> 5;
    const int g = t & 31;
    const char* kvb = (const char*)kv_t;
    const int go = g * 16;

    #pragma unroll 1
    for (int pass = 0; pass < 2; ++pass) {
        const int jj = blockIdx.x + pass * 1024;
        const int y = jj >> 4;
        const int x = ((jj & 15) << 3) + pi;
        const int pix = y * W + x;

        const float dx = deform[pix];
        const float dy = deform[HW + pix];
        const float fdx = floorf(dx), fdy = floorf(dy);
        const float fx = dx - fdx, fy = dy - fdy;
        const float wx0 = 1.f - fx, wx1 = fx, wy0 = 1.f - fy, wy1 = fy;
        const int x0 = x - 2 + (int)fdx;
        const int y0 = y - 2 + (int)fdy;

        int   coff[6], roff[6];
        float colv[6], rowv[6];
        #pragma unroll
        for (int j = 0; j < 6; ++j) {
            int xc = x0 + j, yc = y0 + j;
            colv[j] = ((unsigned)xc <= 127u) ? 1.f : 0.f;
            rowv[j] = ((unsigned)yc <= 127u) ? 1.f : 0.f;
            coff[j] = (min(max(xc, 0), 127) << 10) + go;
            roff[j] = min(max(yc, 0), 127) << 17;
        }

        float4 q4 = *(const float4*)(q_t + (size_t)pix * C + 4 * g);
        q4.x *= 0.25f; q4.y *= 0.25f; q4.z *= 0.25f; q4.w *= 0.25f;

        float d[36];
        #pragma unroll
        for (int jy = 0; jy < 6; ++jy) {
            #pragma unroll
            for (int jx = 0; jx < 6; ++jx) {
                float4 k = *(const float4*)(kvb + (roff[jy] + coff[jx]));
                float dd = q4.x * k.x + q4.y * k.y + q4.z * k.z + q4.w * k.w;
                d[jy * 6 + jx] = dd * (rowv[jy] * colv[jx]);
            }
        }

        float s[25];
        #pragma unroll
        for (int iy = 0; iy < 5; ++iy) {
            #pragma unroll
            for (int ix = 0; ix < 5; ++ix) {
                float sp = wy0 * (wx0 * d[iy * 6 + ix]       + wx1 * d[iy * 6 + ix + 1])
                         + wy1 * (wx0 * d[(iy + 1) * 6 + ix] + wx1 * d[(iy + 1) * 6 + ix + 1]);
                sp += __shfl_xor(sp, 1);
                sp += __shfl_xor(sp, 2);
                s[iy * 5 + ix] = sp;
            }
        }

        float m = s[0];
        #pragma unroll
        for (int p = 1; p < 25; ++p) m = fmaxf(m, s[p]);
        float sum = 0.f;
        #pragma unroll
        for (int p = 0; p < 25; ++p) {
            float e = __expf(s[p] - m);
            s[p] = e;
            sum += e;
        }
        const float inv = 1.f / sum;

        float b[36];
        #pragma unroll
        for (int jy = 0; jy < 6; ++jy) {
            #pragma unroll
            for (int jx = 0; jx < 6; ++jx) {
                float acc = 0.f;
                if (jy < 5  && jx < 5)  acc += wy0 * wx0 * s[jy * 5 + jx];
                if (jy < 5  && jx >= 1) acc += wy0 * wx1 * s[jy * 5 + jx - 1];
                if (jy >= 1 && jx < 5)  acc += wy1 * wx0 * s[(jy - 1) * 5 + jx];
                if (jy >= 1 && jx >= 1) acc += wy1 * wx1 * s[(jy - 1) * 5 + jx - 1];
                b[jy * 6 + jx] = acc * (rowv[jy] * colv[jx]);
            }
        }

        float4 oc = {0.f, 0.f, 0.f, 0.f};
        #pragma unroll
        for (int jy = 0; jy < 6; ++jy) {
            #pragma unroll
            for (int jx = 0; jx < 6; ++jx) {
                float4 v = *(const float4*)(kvb + (roff[jy] + coff[jx]) + 512);
                float bw = b[jy * 6 + jx];
                oc.x += bw * v.x;
                oc.y += bw * v.y;
                oc.z += bw * v.z;
                oc.w += bw * v.w;
            }
        }

        ushort4 ob;
        ob.x = f2bf(oc.x * inv);
        ob.y = f2bf(oc.y * inv);
        ob.z = f2bf(oc.z * inv);
        ob.w = f2bf(oc.w * inv);
        *(ushort4*)(ao_t + (size_t)pix * C + 4 * g) = ob;
    }
}

// ---------------- kernel 4: fc + MLP + residual + stats via MFMA ----------------
// 256 blocks x 256 thr, 64 px/block (2 subtiles of 32). Pipelined staging:
// each phase issues the NEXT weight panel's loads into regs before its GEMM,
// commits to LDS after the sync. Stats -> per-block partials (no atomics).
__global__ __launch_bounds__(256, 2)
void mlp_mfma(const unsigned short* __restrict__ ao_t, const unsigned short* __restrict__ wb,
              const float* __restrict__ b1, const float* __restrict__ b2,
              float* __restrict__ out2, float2* __restrict__ partials) {
    __shared__ unsigned short wbuf[16384];    // 32 KB weight panel
    __shared__ unsigned short l1[64 * 128];   // out1 bf16 (pixel-swizzled)  16 KB
    __shared__ unsigned short lh[64 * 256];   // hid  bf16 (pixel-swizzled)  32 KB
    __shared__ float rs[8];
    const int t = threadIdx.x;
    const int p0 = blockIdx.x * 64;
    const int lane = t & 63, row16 = lane & 15, g = lane >> 4;
    const int w = t >> 6, nh = w & 1, mh = w >> 1;
    const unsigned short* wfc_b = wb + 49152;
    const unsigned short* w1_b  = wb + 65536;
    const unsigned short* w2_b  = wb + 98304;

    short8v r[8];
    stage_load(wfc_b, r, t);
    // B-fragments for GEMM1 (both subtiles) issued early too
    short8v bf[2][4];
    #pragma unroll
    for (int st = 0; st < 2; ++st) {
        int pix = p0 + st * 32 + nh * 16 + row16;
        #pragma unroll
        for (int kk = 0; kk < 4; ++kk)
            bf[st][kk] = *(const short8v*)&ao_t[(size_t)pix * 128 + kk * 32 + g * 8];
    }
    stage_write<4>(r, wbuf, t);
    __syncthreads();

    // ---- GEMM1: out1 = wfc . ao ; prefetch w1 half 0 ----
    stage_load(w1_b, r, t);
    #pragma unroll
    for (int st = 0; st < 2; ++st) {
        const int ploc = st * 32 + nh * 16 + row16;
        const int swz = (ploc & 7) << 3;
        f32x4 acc[4] = {};
        #pragma unroll
        for (int kk = 0; kk < 4; ++kk) {
            #pragma unroll
            for (int f = 0; f < 4; ++f) {
                int row = mh * 64 + f * 16 + row16;
                short8v a = *(const short8v*)&wbuf[(row << 7) + (((kk * 4 + g) ^ (row & 7)) << 3)];
                acc[f] = __builtin_amdgcn_mfma_f32_16x16x32_bf16(a, bf[st][kk], acc[f], 0, 0, 0);
            }
        }
        #pragma unroll
        for (int f = 0; f < 4; ++f)
            #pragma unroll
            for (int e = 0; e < 4; ++e) {
                int o = mh * 64 + f * 16 + g * 4 + e;
                l1[ploc * 128 + (o ^ swz)] = f2bf(acc[f][e]);
            }
    }
    __syncthreads();
    stage_write<4>(r, wbuf, t);
    __syncthreads();

    // ---- GEMM2 halves: hid = leaky(w1 . out1 + b1) ----
    #pragma unroll
    for (int s = 0; s < 2; ++s) {
        if (s == 0) stage_load(w1_b + 16384, r, t);   // prefetch w1 half 1
        else        stage_load(w2_b, r, t);           // prefetch w2 half 0
        #pragma unroll
        for (int st = 0; st < 2; ++st) {
            const int ploc = st * 32 + nh * 16 + row16;
            const int swz = (ploc & 7) << 3;
            f32x4 acc[4] = {};
            #pragma unroll
            for (int kk = 0; kk < 4; ++kk) {
                short8v b = *(const short8v*)&l1[ploc * 128 + ((kk * 32 + g * 8) ^ swz)];
                #pragma unroll
                for (int f = 0; f < 4; ++f) {
                    int row = mh * 64 + f * 16 + row16;
                    short8v a = *(const short8v*)&wbuf[(row << 7) + (((kk * 4 + g) ^ (row & 7)) << 3)];
                    acc[f] = __builtin_amdgcn_mfma_f32_16x16x32_bf16(a, b, acc[f], 0, 0, 0);
                }
            }
            #pragma unroll
            for (int f = 0; f < 4; ++f) {
                int h = s * 128 + mh * 64 + f * 16 + g * 4;
                float4 bb = *(const float4*)&b1[h];
                float hv[4] = {acc[f][0] + bb.x, acc[f][1] + bb.y,
                               acc[f][2] + bb.z, acc[f][3] + bb.w};
                #pragma unroll
                for (int e = 0; e < 4; ++e) {
                    float v = (hv[e] >= 0.f) ? hv[e] : 0.2f * hv[e];
                    lh[ploc * 256 + ((h + e) ^ swz)] = f2bf(v);
                }
            }
        }
        __syncthreads();
        if (s == 0) stage_write<4>(r, wbuf, t);
        else        stage_write<5>(r, wbuf, t);
        __syncthreads();
    }

    // ---- GEMM3 halves: out2 = w2 . hid + b2 + out1 ----
    float lsum = 0.f, lsq = 0.f;
    #pragma unroll
    for (int s = 0; s < 2; ++s) {
        if (s == 0) stage_load(w2_b + 16384, r, t);   // prefetch w2 half 1
        #pragma unroll
        for (int st = 0; st < 2; ++st) {
            const int ploc = st * 32 + nh * 16 + row16;
            const int swz = (ploc & 7) << 3;
            const int pix = p0 + ploc;
            f32x4 acc[2] = {};
            #pragma unroll
            for (int kk = 0; kk < 8; ++kk) {
                short8v b = *(const short8v*)&lh[ploc * 256 + ((kk * 32 + g * 8) ^ swz)];
                #pragma unroll
                for (int f = 0; f < 2; ++f) {
                    int row = mh * 32 + f * 16 + row16;       // local row in [0,64)
                    short8v a = *(const short8v*)&wbuf[(row << 8) + (((kk * 4 + g) ^ (row & 7)) << 3)];
                    acc[f] = __builtin_amdgcn_mfma_f32_16x16x32_bf16(a, b, acc[f], 0, 0, 0);
                }
            }
            #pragma unroll
            for (int f = 0; f < 2; ++f) {
                int ob = s * 64 + mh * 32 + f * 16 + g * 4;
                float4 b2v = *(const float4*)&b2[ob];
                ushort4 res = *(const ushort4*)&l1[ploc * 128 + (ob ^ swz)];
                float bv[4] = {b2v.x, b2v.y, b2v.z, b2v.w};
                unsigned short rr[4] = {res.x, res.y, res.z, res.w};
                #pragma unroll
                for (int e = 0; e < 4; ++e) {
                    float v = acc[f][e] + bf2f(rr[e]) + bv[e];
                    out2[(size_t)(ob + e) * HW + pix] = v;
                    lsum += v;
                    lsq += v * v;
                }
            }
        }
        if (s == 0) {
            __syncthreads();
            stage_write<5>(r, wbuf, t);
            __syncthreads();
        }
    }

    // ---- per-block stats partial (no atomics) ----
    #pragma unroll
    for (int s = 1; s < 64; s <<= 1) {
        lsum += __shfl_xor(lsum, s);
        lsq  += __shfl_xor(lsq, s);
    }
    if (lane == 0) { rs[w] = lsum; rs[4 + w] = lsq; }
    __syncthreads();
    if (t == 0)
        partials[blockIdx.x] = make_float2(rs[0] + rs[1] + rs[2] + rs[3],
                                           rs[4] + rs[5] + rs[6] + rs[7]);
}

// ---------------- kernel 5: reduce 256 block partials -> accum ----------------
__global__ void reduce_stats(const float2* __restrict__ partials, float* __restrict__ acc) {
    __shared__ float rs[8];
    const int t = threadIdx.x;   // 256
    float2 p = partials[t];
    float a = p.x, b = p.y;
    #pragma unroll
    for (int s = 1; s < 64; s <<= 1) {
        a += __shfl_xor(a, s);
        b += __shfl_xor(b, s);
    }
    int w = t >> 6;
    if ((t & 63) == 0) { rs[w] = a; rs[4 + w] = b; }
    __syncthreads();
    if (t == 0) {
        acc[0] = rs[0] + rs[1] + rs[2] + rs[3];
        acc[1] = rs[4] + rs[5] + rs[6] + rs[7];
    }
}

// ---------------- kernel 6: global layernorm (in place on d_out) ----------------
__global__ void norm_kernel(float* __restrict__ out2, const float* __restrict__ accum,
                            const float* __restrict__ gn_w, const float* __restrict__ gn_b) {
    const int gid = blockIdx.x * 256 + threadIdx.x;
    const float invN = 1.f / 2097152.f;
    float mean = accum[0] * invN;
    float var = accum[1] * invN - mean * mean;
    float rstd = rsqrtf(var + 1e-5f);
    int base = gid * 4;
    int o = base >> 14;
    float g = gn_w[o] * rstd;
    float b = gn_b[o];
    float4 v = *(const float4*)(out2 + base);
    float4 r;
    r.x = (v.x - mean) * g + b;
    r.y = (v.y - mean) * g + b;
    r.z = (v.z - mean) * g + b;
    r.w = (v.w - mean) * g + b;
    *(float4*)(out2 + base) = r;
}

extern "C" void kernel_launch(void* const* d_in, const int* in_sizes, int n_in,
                              void* d_out, int out_size, void* d_ws, size_t ws_size,
                              hipStream_t stream) {
    const float* query  = (const float*)d_in[0];
    const float* key    = (const float*)d_in[1];
    const float* value  = (const float*)d_in[2];
    const float* deform = (const float*)d_in[3];
    const float* w_q    = (const float*)d_in[4];
    const float* w_k    = (const float*)d_in[5];
    const float* w_v    = (const float*)d_in[6];
    const float* w_fc   = (const float*)d_in[7];
    const float* mlp_w1 = (const float*)d_in[8];
    const float* mlp_b1 = (const float*)d_in[9];
    const float* mlp_w2 = (const float*)d_in[10];
    const float* mlp_b2 = (const float*)d_in[11];
    const float* gn_w   = (const float*)d_in[12];
    const float* gn_b   = (const float*)d_in[13];

    float* out = (float*)d_out;
    char* wsb  = (char*)d_ws;

    // ws layout (bytes): q_t f32 [0,8M) | kv_t f32 [8M,24M) | ao bf16 [24M,28M)
    //                    | wb bf16 [28M, 28M+256K) | acc [29M,+8) | partials [29M+4K, +2K)
    float* q_t = (float*)wsb;
    float* kv_t = (float*)(wsb + ((size_t)8 << 20));
    unsigned short* ao_t = (unsigned short*)(wsb + ((size_t)24 << 20));
    unsigned short* wb = (unsigned short*)(wsb + ((size_t)28 << 20));
    float* acc = (float*)(wsb + ((size_t)29 << 20));
    float2* partials = (float2*)(wsb + ((size_t)29 << 20) + 4096);

    prep_weights<<<512, 256, 0, stream>>>(w_q, w_k, w_v, w_fc, mlp_w1, mlp_w2, wb);
    qkv_mfma<<<512, 256, 0, stream>>>(query, key, value, wb, q_t, kv_t);
    attn_kernel<<<1024, 256, 0, stream>>>(q_t, kv_t, deform, ao_t);
    mlp_mfma<<<256, 256, 0, stream>>>(ao_t, wb, mlp_b1, mlp_b2, out, partials);
    reduce_stats<<<1, 256, 0, stream>>>(partials, acc);
    norm_kernel<<<2048, 256, 0, stream>>>(out, acc, gn_w, gn_b);
}

// Round 10
// 64.648 us; speedup vs baseline: 10.2126x; 1.2681x over previous
//
#include <hip/hip_runtime.h>
#include <hip/hip_bf16.h>

#define HW 16384
#define W 128
#define C 128
#define HID 256

typedef __attribute__((ext_vector_type(8))) short short8v;
typedef __attribute__((ext_vector_type(4))) float f32x4;

__device__ __forceinline__ unsigned short f2bf(float f) {
    union { float f; unsigned u; } x; x.f = f;
    unsigned r = x.u + 0x7FFF + ((x.u >> 16) & 1);
    return (unsigned short)(r >> 16);
}
__device__ __forceinline__ float bf2f(unsigned short b) {
    union { unsigned u; float f; } x; x.u = ((unsigned)b) << 16;
    return x.f;
}

// ---- async-stage split: issue 32KB panel (8 x 16B per thread) into regs ----
__device__ __forceinline__ void stage_load(const unsigned short* __restrict__ src,
                                           short8v* r, int t) {
    #pragma unroll
    for (int c = 0; c < 8; ++c)
        r[c] = *(const short8v*)(src + (size_t)(c * 256 + t) * 8);
}
// ---- commit regs to LDS, XOR-swizzled: granule col ^= (row&7). RSH=log2(granules/row)
template<int RSH>
__device__ __forceinline__ void stage_write(const short8v* r, unsigned short* lds, int t) {
    #pragma unroll
    for (int c = 0; c < 8; ++c) {
        int gi = c * 256 + t;
        int row = gi >> RSH, colg = gi & ((1 << RSH) - 1);
        *(short8v*)(lds + (size_t)(((row << RSH) + (colg ^ (row & 7))) << 3)) = r[c];
    }
}
template<int RSH>
__device__ __forceinline__ void stage32(const unsigned short* __restrict__ src,
                                        unsigned short* lds, int t) {
    #pragma unroll
    for (int c = 0; c < 8; ++c) {
        int gi = c * 256 + t;
        int row = gi >> RSH, colg = gi & ((1 << RSH) - 1);
        short8v v = *(const short8v*)(src + (size_t)gi * 8);
        *(short8v*)(lds + (size_t)(((row << RSH) + (colg ^ (row & 7))) << 3)) = v;
    }
}

// ---------------- kernel 1: convert all weights to bf16 ----------------
// layout in wb: wq[16384] wk[16384] wv[16384] wfc[16384] w1[32768] w2[32768]
__global__ void prep_weights(const float* __restrict__ wq, const float* __restrict__ wk,
                             const float* __restrict__ wv, const float* __restrict__ wfc,
                             const float* __restrict__ w1, const float* __restrict__ w2,
                             unsigned short* __restrict__ wb) {
    int i = blockIdx.x * 256 + threadIdx.x;   // 0..131071
    float v;
    if (i < 16384)       v = wq[i];
    else if (i < 32768)  v = wk[i - 16384];
    else if (i < 49152)  v = wv[i - 32768];
    else if (i < 65536)  v = wfc[i - 49152];
    else if (i < 98304)  v = w1[i - 65536];
    else                 v = w2[i - 98304];
    wb[i] = f2bf(v);
}

// ---------------- kernel 2: q/k/v 1x1 convs via MFMA, LDS-staged weights ----------------
// Outputs bf16: q_t[pix][128]; kv_t[pix][256] (k 0..127 | v 128..255).
__global__ __launch_bounds__(256, 2)
void qkv_mfma(const float* __restrict__ q_in, const float* __restrict__ k_in,
              const float* __restrict__ v_in, const unsigned short* __restrict__ wb,
              unsigned short* __restrict__ q_t, unsigned short* __restrict__ kv_t) {
    __shared__ unsigned short lx[3][32 * 128];   // 24 KB inputs (pixel-swizzled)
    __shared__ unsigned short wbuf[16384];       // 32 KB weight panel
    const int t = threadIdx.x;
    const int p0 = blockIdx.x * 32;
    const int lane = t & 63, row16 = lane & 15, g = lane >> 4;
    const int w = t >> 6, nh = w & 1, mh = w >> 1;
    const int ploc = nh * 16 + row16;
    const int pix = p0 + ploc;
    const int swz = (ploc & 7) << 3;

    stage32<4>(wb, wbuf, t);    // wq, in flight during x-tile conversion

    const float* ins[3] = {q_in, k_in, v_in};
    #pragma unroll
    for (int m = 0; m < 3; ++m) {
        #pragma unroll
        for (int it = 0; it < 16; ++it) {
            int e = t + 256 * it;          // 0..4095
            int p = e & 31, c = e >> 5;
            lx[m][p * 128 + (c ^ ((p & 7) << 3))] = f2bf(ins[m][c * HW + p0 + p]);
        }
    }

    #pragma unroll 1
    for (int m = 0; m < 3; ++m) {
        if (m > 0) {
            __syncthreads();               // previous GEMM done reading wbuf
            stage32<4>(wb + m * 16384, wbuf, t);
        }
        __syncthreads();                   // staging (and lx on m=0) visible

        f32x4 acc[4] = {};
        #pragma unroll
        for (int kk = 0; kk < 4; ++kk) {
            short8v b = *(const short8v*)&lx[m][ploc * 128 + ((kk * 32 + g * 8) ^ swz)];
            #pragma unroll
            for (int f = 0; f < 4; ++f) {
                int row = mh * 64 + f * 16 + row16;
                short8v a = *(const short8v*)&wbuf[(row << 7) + (((kk * 4 + g) ^ (row & 7)) << 3)];
                acc[f] = __builtin_amdgcn_mfma_f32_16x16x32_bf16(a, b, acc[f], 0, 0, 0);
            }
        }
        #pragma unroll
        for (int f = 0; f < 4; ++f) {
            int o = mh * 64 + f * 16 + g * 4;
            ushort4 st;
            st.x = f2bf(acc[f][0]); st.y = f2bf(acc[f][1]);
            st.z = f2bf(acc[f][2]); st.w = f2bf(acc[f][3]);
            if (m == 0)      *(ushort4*)&q_t[(size_t)pix * 128 + o] = st;
            else if (m == 1) *(ushort4*)&kv_t[(size_t)pix * 256 + o] = st;
            else             *(ushort4*)&kv_t[(size_t)pix * 256 + 128 + o] = st;
        }
    }
}

// ---------------- kernel 3: deformable attention, factorized 6x6 corner grid ----------------
// bf16 q/kv (8B gathers). Single pass, 2048 blocks, linear bid->tile for the
// dispatch-order sliding L2 window. 8 px/block, 32 thr/px, 4 ch/thr.
__global__ __launch_bounds__(256, 2)
void attn_kernel(const unsigned short* __restrict__ q_t, const unsigned short* __restrict__ kv_t,
                 const float* __restrict__ deform, unsigned short* __restrict__ ao_t) {
    const int t = threadIdx.x;
    const int pi = t >> 5;
    const int g = t & 31;
    const char* kvb = (const char*)kv_t;
    const int go = g * 8;

    const int jj = blockIdx.x;
    const int y = jj >> 4;
    const int x = ((jj & 15) << 3) + pi;
    const int pix = y * W + x;

    const float dx = deform[pix];
    const float dy = deform[HW + pix];
    const float fdx = floorf(dx), fdy = floorf(dy);
    const float fx = dx - fdx, fy = dy - fdy;
    const float wx0 = 1.f - fx, wx1 = fx, wy0 = 1.f - fy, wy1 = fy;
    const int x0 = x - 2 + (int)fdx;
    const int y0 = y - 2 + (int)fdy;

    int   coff[6], roff[6];
    float colv[6], rowv[6];
    #pragma unroll
    for (int j = 0; j < 6; ++j) {
        int xc = x0 + j, yc = y0 + j;
        colv[j] = ((unsigned)xc <= 127u) ? 1.f : 0.f;
        rowv[j] = ((unsigned)yc <= 127u) ? 1.f : 0.f;
        coff[j] = (min(max(xc, 0), 127) << 9) + go;   // x*512B + channel byte off
        roff[j] = min(max(yc, 0), 127) << 16;         // y*64KB
    }

    ushort4 qu = *(const ushort4*)(q_t + (size_t)pix * C + 4 * g);
    float4 q4;
    q4.x = bf2f(qu.x) * 0.25f; q4.y = bf2f(qu.y) * 0.25f;   // 1/sqrt(16)
    q4.z = bf2f(qu.z) * 0.25f; q4.w = bf2f(qu.w) * 0.25f;

    // ---- phase A: 36 per-thread partial dots ----
    float d[36];
    #pragma unroll
    for (int jy = 0; jy < 6; ++jy) {
        #pragma unroll
        for (int jx = 0; jx < 6; ++jx) {
            ushort4 k = *(const ushort4*)(kvb + (roff[jy] + coff[jx]));
            float dd = q4.x * bf2f(k.x) + q4.y * bf2f(k.y)
                     + q4.z * bf2f(k.z) + q4.w * bf2f(k.w);
            d[jy * 6 + jx] = dd * (rowv[jy] * colv[jx]);
        }
    }

    // ---- scores: bilinear combine + head reduce (4 lanes/head) ----
    float s[25];
    #pragma unroll
    for (int iy = 0; iy < 5; ++iy) {
        #pragma unroll
        for (int ix = 0; ix < 5; ++ix) {
            float sp = wy0 * (wx0 * d[iy * 6 + ix]       + wx1 * d[iy * 6 + ix + 1])
                     + wy1 * (wx0 * d[(iy + 1) * 6 + ix] + wx1 * d[(iy + 1) * 6 + ix + 1]);
            sp += __shfl_xor(sp, 1);
            sp += __shfl_xor(sp, 2);
            s[iy * 5 + ix] = sp;
        }
    }

    // ---- softmax over 25 (in registers; identical in all 4 head lanes) ----
    float m = s[0];
    #pragma unroll
    for (int p = 1; p < 25; ++p) m = fmaxf(m, s[p]);
    float sum = 0.f;
    #pragma unroll
    for (int p = 0; p < 25; ++p) {
        float e = __expf(s[p] - m);
        s[p] = e;
        sum += e;
    }
    const float inv = 1.f / sum;

    // ---- corner weights: transpose bilinear of probs, fold validity ----
    float b[36];
    #pragma unroll
    for (int jy = 0; jy < 6; ++jy) {
        #pragma unroll
        for (int jx = 0; jx < 6; ++jx) {
            float acc = 0.f;
            if (jy < 5  && jx < 5)  acc += wy0 * wx0 * s[jy * 5 + jx];
            if (jy < 5  && jx >= 1) acc += wy0 * wx1 * s[jy * 5 + jx - 1];
            if (jy >= 1 && jx < 5)  acc += wy1 * wx0 * s[(jy - 1) * 5 + jx];
            if (jy >= 1 && jx >= 1) acc += wy1 * wx1 * s[(jy - 1) * 5 + jx - 1];
            b[jy * 6 + jx] = acc * (rowv[jy] * colv[jx]);
        }
    }

    // ---- phase B: 36 V gathers ----
    float4 oc = {0.f, 0.f, 0.f, 0.f};
    #pragma unroll
    for (int jy = 0; jy < 6; ++jy) {
        #pragma unroll
        for (int jx = 0; jx < 6; ++jx) {
            ushort4 v = *(const ushort4*)(kvb + (roff[jy] + coff[jx]) + 256);
            float bw = b[jy * 6 + jx];
            oc.x += bw * bf2f(v.x);
            oc.y += bw * bf2f(v.y);
            oc.z += bw * bf2f(v.z);
            oc.w += bw * bf2f(v.w);
        }
    }

    ushort4 ob;
    ob.x = f2bf(oc.x * inv);
    ob.y = f2bf(oc.y * inv);
    ob.z = f2bf(oc.z * inv);
    ob.w = f2bf(oc.w * inv);
    *(ushort4*)(ao_t + (size_t)pix * C + 4 * g) = ob;
}

// ---------------- kernel 4: fc + MLP + residual + stats via MFMA ----------------
// 256 blocks x 256 thr, 64 px/block (2 subtiles of 32). Pipelined staging:
// each phase issues the NEXT weight panel's loads into regs before its GEMM,
// commits to LDS after the sync. Stats -> per-block partials (no atomics).
__global__ __launch_bounds__(256, 2)
void mlp_mfma(const unsigned short* __restrict__ ao_t, const unsigned short* __restrict__ wb,
              const float* __restrict__ b1, const float* __restrict__ b2,
              float* __restrict__ out2, float2* __restrict__ partials) {
    __shared__ unsigned short wbuf[16384];    // 32 KB weight panel
    __shared__ unsigned short l1[64 * 128];   // out1 bf16 (pixel-swizzled)  16 KB
    __shared__ unsigned short lh[64 * 256];   // hid  bf16 (pixel-swizzled)  32 KB
    __shared__ float rs[8];
    const int t = threadIdx.x;
    const int p0 = blockIdx.x * 64;
    const int lane = t & 63, row16 = lane & 15, g = lane >> 4;
    const int w = t >> 6, nh = w & 1, mh = w >> 1;
    const unsigned short* wfc_b = wb + 49152;
    const unsigned short* w1_b  = wb + 65536;
    const unsigned short* w2_b  = wb + 98304;

    short8v r[8];
    stage_load(wfc_b, r, t);
    // B-fragments for GEMM1 (both subtiles) issued early too
    short8v bf[2][4];
    #pragma unroll
    for (int st = 0; st < 2; ++st) {
        int pix = p0 + st * 32 + nh * 16 + row16;
        #pragma unroll
        for (int kk = 0; kk < 4; ++kk)
            bf[st][kk] = *(const short8v*)&ao_t[(size_t)pix * 128 + kk * 32 + g * 8];
    }
    stage_write<4>(r, wbuf, t);
    __syncthreads();

    // ---- GEMM1: out1 = wfc . ao ; prefetch w1 half 0 ----
    stage_load(w1_b, r, t);
    #pragma unroll
    for (int st = 0; st < 2; ++st) {
        const int ploc = st * 32 + nh * 16 + row16;
        const int swz = (ploc & 7) << 3;
        f32x4 acc[4] = {};
        #pragma unroll
        for (int kk = 0; kk < 4; ++kk) {
            #pragma unroll
            for (int f = 0; f < 4; ++f) {
                int row = mh * 64 + f * 16 + row16;
                short8v a = *(const short8v*)&wbuf[(row << 7) + (((kk * 4 + g) ^ (row & 7)) << 3)];
                acc[f] = __builtin_amdgcn_mfma_f32_16x16x32_bf16(a, bf[st][kk], acc[f], 0, 0, 0);
            }
        }
        #pragma unroll
        for (int f = 0; f < 4; ++f)
            #pragma unroll
            for (int e = 0; e < 4; ++e) {
                int o = mh * 64 + f * 16 + g * 4 + e;
                l1[ploc * 128 + (o ^ swz)] = f2bf(acc[f][e]);
            }
    }
    __syncthreads();
    stage_write<4>(r, wbuf, t);
    __syncthreads();

    // ---- GEMM2 halves: hid = leaky(w1 . out1 + b1) ----
    #pragma unroll
    for (int s = 0; s < 2; ++s) {
        if (s == 0) stage_load(w1_b + 16384, r, t);   // prefetch w1 half 1
        else        stage_load(w2_b, r, t);           // prefetch w2 half 0
        #pragma unroll
        for (int st = 0; st < 2; ++st) {
            const int ploc = st * 32 + nh * 16 + row16;
            const int swz = (ploc & 7) << 3;
            f32x4 acc[4] = {};
            #pragma unroll
            for (int kk = 0; kk < 4; ++kk) {
                short8v b = *(const short8v*)&l1[ploc * 128 + ((kk * 32 + g * 8) ^ swz)];
                #pragma unroll
                for (int f = 0; f < 4; ++f) {
                    int row = mh * 64 + f * 16 + row16;
                    short8v a = *(const short8v*)&wbuf[(row << 7) + (((kk * 4 + g) ^ (row & 7)) << 3)];
                    acc[f] = __builtin_amdgcn_mfma_f32_16x16x32_bf16(a, b, acc[f], 0, 0, 0);
                }
            }
            #pragma unroll
            for (int f = 0; f < 4; ++f) {
                int h = s * 128 + mh * 64 + f * 16 + g * 4;
                float4 bb = *(const float4*)&b1[h];
                float hv[4] = {acc[f][0] + bb.x, acc[f][1] + bb.y,
                               acc[f][2] + bb.z, acc[f][3] + bb.w};
                #pragma unroll
                for (int e = 0; e < 4; ++e) {
                    float v = (hv[e] >= 0.f) ? hv[e] : 0.2f * hv[e];
                    lh[ploc * 256 + ((h + e) ^ swz)] = f2bf(v);
                }
            }
        }
        __syncthreads();
        if (s == 0) stage_write<4>(r, wbuf, t);
        else        stage_write<5>(r, wbuf, t);
        __syncthreads();
    }

    // ---- GEMM3 halves: out2 = w2 . hid + b2 + out1 ----
    float lsum = 0.f, lsq = 0.f;
    #pragma unroll
    for (int s = 0; s < 2; ++s) {
        if (s == 0) stage_load(w2_b + 16384, r, t);   // prefetch w2 half 1
        #pragma unroll
        for (int st = 0; st < 2; ++st) {
            const int ploc = st * 32 + nh * 16 + row16;
            const int swz = (ploc & 7) << 3;
            const int pix = p0 + ploc;
            f32x4 acc[2] = {};
            #pragma unroll
            for (int kk = 0; kk < 8; ++kk) {
                short8v b = *(const short8v*)&lh[ploc * 256 + ((kk * 32 + g * 8) ^ swz)];
                #pragma unroll
                for (int f = 0; f < 2; ++f) {
                    int row = mh * 32 + f * 16 + row16;       // local row in [0,64)
                    short8v a = *(const short8v*)&wbuf[(row << 8) + (((kk * 4 + g) ^ (row & 7)) << 3)];
                    acc[f] = __builtin_amdgcn_mfma_f32_16x16x32_bf16(a, b, acc[f], 0, 0, 0);
                }
            }
            #pragma unroll
            for (int f = 0; f < 2; ++f) {
                int ob = s * 64 + mh * 32 + f * 16 + g * 4;
                float4 b2v = *(const float4*)&b2[ob];
                ushort4 res = *(const ushort4*)&l1[ploc * 128 + (ob ^ swz)];
                float bv[4] = {b2v.x, b2v.y, b2v.z, b2v.w};
                unsigned short rr[4] = {res.x, res.y, res.z, res.w};
                #pragma unroll
                for (int e = 0; e < 4; ++e) {
                    float v = acc[f][e] + bf2f(rr[e]) + bv[e];
                    out2[(size_t)(ob + e) * HW + pix] = v;
                    lsum += v;
                    lsq += v * v;
                }
            }
        }
        if (s == 0) {
            __syncthreads();
            stage_write<5>(r, wbuf, t);
            __syncthreads();
        }
    }

    // ---- per-block stats partial (no atomics) ----
    #pragma unroll
    for (int s = 1; s < 64; s <<= 1) {
        lsum += __shfl_xor(lsum, s);
        lsq  += __shfl_xor(lsq, s);
    }
    if (lane == 0) { rs[w] = lsum; rs[4 + w] = lsq; }
    __syncthreads();
    if (t == 0)
        partials[blockIdx.x] = make_float2(rs[0] + rs[1] + rs[2] + rs[3],
                                           rs[4] + rs[5] + rs[6] + rs[7]);
}

// ---------------- kernel 5: reduce 256 block partials -> accum ----------------
__global__ void reduce_stats(const float2* __restrict__ partials, float* __restrict__ acc) {
    __shared__ float rs[8];
    const int t = threadIdx.x;   // 256
    float2 p = partials[t];
    float a = p.x, b = p.y;
    #pragma unroll
    for (int s = 1; s < 64; s <<= 1) {
        a += __shfl_xor(a, s);
        b += __shfl_xor(b, s);
    }
    int w = t >> 6;
    if ((t & 63) == 0) { rs[w] = a; rs[4 + w] = b; }
    __syncthreads();
    if (t == 0) {
        acc[0] = rs[0] + rs[1] + rs[2] + rs[3];
        acc[1] = rs[4] + rs[5] + rs[6] + rs[7];
    }
}

// ---------------- kernel 6: global layernorm (in place on d_out) ----------------
__global__ void norm_kernel(float* __restrict__ out2, const float* __restrict__ accum,
                            const float* __restrict__ gn_w, const float* __restrict__ gn_b) {
    const int gid = blockIdx.x * 256 + threadIdx.x;
    const float invN = 1.f / 2097152.f;
    float mean = accum[0] * invN;
    float var = accum[1] * invN - mean * mean;
    float rstd = rsqrtf(var + 1e-5f);
    int base = gid * 4;
    int o = base >> 14;
    float g = gn_w[o] * rstd;
    float b = gn_b[o];
    float4 v = *(const float4*)(out2 + base);
    float4 r;
    r.x = (v.x - mean) * g + b;
    r.y = (v.y - mean) * g + b;
    r.z = (v.z - mean) * g + b;
    r.w = (v.w - mean) * g + b;
    *(float4*)(out2 + base) = r;
}

extern "C" void kernel_launch(void* const* d_in, const int* in_sizes, int n_in,
                              void* d_out, int out_size, void* d_ws, size_t ws_size,
                              hipStream_t stream) {
    const float* query  = (const float*)d_in[0];
    const float* key    = (const float*)d_in[1];
    const float* value  = (const float*)d_in[2];
    const float* deform = (const float*)d_in[3];
    const float* w_q    = (const float*)d_in[4];
    const float* w_k    = (const float*)d_in[5];
    const float* w_v    = (const float*)d_in[6];
    const float* w_fc   = (const float*)d_in[7];
    const float* mlp_w1 = (const float*)d_in[8];
    const float* mlp_b1 = (const float*)d_in[9];
    const float* mlp_w2 = (const float*)d_in[10];
    const float* mlp_b2 = (const float*)d_in[11];
    const float* gn_w   = (const float*)d_in[12];
    const float* gn_b   = (const float*)d_in[13];

    float* out = (float*)d_out;
    char* wsb  = (char*)d_ws;

    // ws layout (bytes): q_t bf16 [0,4M) | kv_t bf16 [4M,12M) | ao bf16 [12M,16M)
    //                    | wb bf16 [16M,+256K) | acc [17M,+8) | partials [17M+4K,+2K)
    unsigned short* q_t  = (unsigned short*)wsb;
    unsigned short* kv_t = (unsigned short*)(wsb + ((size_t)4 << 20));
    unsigned short* ao_t = (unsigned short*)(wsb + ((size_t)12 << 20));
    unsigned short* wb   = (unsigned short*)(wsb + ((size_t)16 << 20));
    float* acc = (float*)(wsb + ((size_t)17 << 20));
    float2* partials = (float2*)(wsb + ((size_t)17 << 20) + 4096);

    prep_weights<<<512, 256, 0, stream>>>(w_q, w_k, w_v, w_fc, mlp_w1, mlp_w2, wb);
    qkv_mfma<<<512, 256, 0, stream>>>(query, key, value, wb, q_t, kv_t);
    attn_kernel<<<2048, 256, 0, stream>>>(q_t, kv_t, deform, ao_t);
    mlp_mfma<<<256, 256, 0, stream>>>(ao_t, wb, mlp_b1, mlp_b2, out, partials);
    reduce_stats<<<1, 256, 0, stream>>>(partials, acc);
    norm_kernel<<<2048, 256, 0, stream>>>(out, acc, gn_w, gn_b);
}

// Round 11
// 52.932 us; speedup vs baseline: 12.4731x; 1.2213x over previous
//
#include <hip/hip_runtime.h>
#include <hip/hip_bf16.h>

#define HW 16384
#define W 128
#define C 128
#define HID 256

typedef __attribute__((ext_vector_type(8))) short short8v;
typedef __attribute__((ext_vector_type(4))) float f32x4;

__device__ __forceinline__ unsigned short f2bf(float f) {
    union { float f; unsigned u; } x; x.f = f;
    unsigned r = x.u + 0x7FFF + ((x.u >> 16) & 1);
    return (unsigned short)(r >> 16);
}
__device__ __forceinline__ float bf2f(unsigned short b) {
    union { unsigned u; float f; } x; x.u = ((unsigned)b) << 16;
    return x.f;
}

// ---- async-stage split: issue 32KB panel (8 x 16B per thread) into regs ----
__device__ __forceinline__ void stage_load(const unsigned short* __restrict__ src,
                                           short8v* r, int t) {
    #pragma unroll
    for (int c = 0; c < 8; ++c)
        r[c] = *(const short8v*)(src + (size_t)(c * 256 + t) * 8);
}
// ---- commit regs to LDS, XOR-swizzled: granule col ^= (row&7). RSH=log2(granules/row)
template<int RSH>
__device__ __forceinline__ void stage_write(const short8v* r, unsigned short* lds, int t) {
    #pragma unroll
    for (int c = 0; c < 8; ++c) {
        int gi = c * 256 + t;
        int row = gi >> RSH, colg = gi & ((1 << RSH) - 1);
        *(short8v*)(lds + (size_t)(((row << RSH) + (colg ^ (row & 7))) << 3)) = r[c];
    }
}
template<int RSH>
__device__ __forceinline__ void stage32(const unsigned short* __restrict__ src,
                                        unsigned short* lds, int t) {
    #pragma unroll
    for (int c = 0; c < 8; ++c) {
        int gi = c * 256 + t;
        int row = gi >> RSH, colg = gi & ((1 << RSH) - 1);
        short8v v = *(const short8v*)(src + (size_t)gi * 8);
        *(short8v*)(lds + (size_t)(((row << RSH) + (colg ^ (row & 7))) << 3)) = v;
    }
}

// ---------------- kernel 1: convert all weights to bf16 ----------------
// layout in wb: wq[16384] wk[16384] wv[16384] wfc[16384] w1[32768] w2[32768]
__global__ void prep_weights(const float* __restrict__ wq, const float* __restrict__ wk,
                             const float* __restrict__ wv, const float* __restrict__ wfc,
                             const float* __restrict__ w1, const float* __restrict__ w2,
                             unsigned short* __restrict__ wb) {
    int i = blockIdx.x * 256 + threadIdx.x;   // 0..131071
    float v;
    if (i < 16384)       v = wq[i];
    else if (i < 32768)  v = wk[i - 16384];
    else if (i < 49152)  v = wv[i - 32768];
    else if (i < 65536)  v = wfc[i - 49152];
    else if (i < 98304)  v = w1[i - 65536];
    else                 v = w2[i - 98304];
    wb[i] = f2bf(v);
}

// ---------------- kernel 2: q/k/v 1x1 convs via MFMA, LDS-staged weights ----------------
// Outputs bf16: q_t[pix][128]; kv_t[pix][256] (k 0..127 | v 128..255).
__global__ __launch_bounds__(256, 2)
void qkv_mfma(const float* __restrict__ q_in, const float* __restrict__ k_in,
              const float* __restrict__ v_in, const unsigned short* __restrict__ wb,
              unsigned short* __restrict__ q_t, unsigned short* __restrict__ kv_t) {
    __shared__ unsigned short lx[3][32 * 128];   // 24 KB inputs (pixel-swizzled)
    __shared__ unsigned short wbuf[16384];       // 32 KB weight panel
    const int t = threadIdx.x;
    const int p0 = blockIdx.x * 32;
    const int lane = t & 63, row16 = lane & 15, g = lane >> 4;
    const int w = t >> 6, nh = w & 1, mh = w >> 1;
    const int ploc = nh * 16 + row16;
    const int pix = p0 + ploc;
    const int swz = (ploc & 7) << 3;

    stage32<4>(wb, wbuf, t);    // wq, in flight during x-tile conversion

    const float* ins[3] = {q_in, k_in, v_in};
    #pragma unroll
    for (int m = 0; m < 3; ++m) {
        #pragma unroll
        for (int it = 0; it < 16; ++it) {
            int e = t + 256 * it;          // 0..4095
            int p = e & 31, c = e >> 5;
            lx[m][p * 128 + (c ^ ((p & 7) << 3))] = f2bf(ins[m][c * HW + p0 + p]);
        }
    }

    #pragma unroll 1
    for (int m = 0; m < 3; ++m) {
        if (m > 0) {
            __syncthreads();               // previous GEMM done reading wbuf
            stage32<4>(wb + m * 16384, wbuf, t);
        }
        __syncthreads();                   // staging (and lx on m=0) visible

        f32x4 acc[4] = {};
        #pragma unroll
        for (int kk = 0; kk < 4; ++kk) {
            short8v b = *(const short8v*)&lx[m][ploc * 128 + ((kk * 32 + g * 8) ^ swz)];
            #pragma unroll
            for (int f = 0; f < 4; ++f) {
                int row = mh * 64 + f * 16 + row16;
                short8v a = *(const short8v*)&wbuf[(row << 7) + (((kk * 4 + g) ^ (row & 7)) << 3)];
                acc[f] = __builtin_amdgcn_mfma_f32_16x16x32_bf16(a, b, acc[f], 0, 0, 0);
            }
        }
        #pragma unroll
        for (int f = 0; f < 4; ++f) {
            int o = mh * 64 + f * 16 + g * 4;
            ushort4 st;
            st.x = f2bf(acc[f][0]); st.y = f2bf(acc[f][1]);
            st.z = f2bf(acc[f][2]); st.w = f2bf(acc[f][3]);
            if (m == 0)      *(ushort4*)&q_t[(size_t)pix * 128 + o] = st;
            else if (m == 1) *(ushort4*)&kv_t[(size_t)pix * 256 + o] = st;
            else             *(ushort4*)&kv_t[(size_t)pix * 256 + 128 + o] = st;
        }
    }
}

// ---------------- kernel 3: deformable attention, factorized 6x6 corner grid ----------------
// bf16 q/kv, 16B gathers: 16 thr/px, 8 ch/thr, 16 px/block. 1024 blocks,
// linear bid->tile (dispatch-order sliding L2 window).
__global__ __launch_bounds__(256, 2)
void attn_kernel(const unsigned short* __restrict__ q_t, const unsigned short* __restrict__ kv_t,
                 const float* __restrict__ deform, unsigned short* __restrict__ ao_t) {
    const int t = threadIdx.x;
    const int pi = t >> 4;     // pixel within block (16)
    const int g = t & 15;      // channel group (8 ch = 16 B)
    const char* kvb = (const char*)kv_t;
    const int go = g * 16;

    const int jj = blockIdx.x;
    const int y = jj >> 3;
    const int x = ((jj & 7) << 4) + pi;
    const int pix = y * W + x;

    const float dx = deform[pix];
    const float dy = deform[HW + pix];
    const float fdx = floorf(dx), fdy = floorf(dy);
    const float fx = dx - fdx, fy = dy - fdy;
    const float wx0 = 1.f - fx, wx1 = fx, wy0 = 1.f - fy, wy1 = fy;
    const int x0 = x - 2 + (int)fdx;
    const int y0 = y - 2 + (int)fdy;

    int   coff[6], roff[6];
    float colv[6], rowv[6];
    #pragma unroll
    for (int j = 0; j < 6; ++j) {
        int xc = x0 + j, yc = y0 + j;
        colv[j] = ((unsigned)xc <= 127u) ? 1.f : 0.f;
        rowv[j] = ((unsigned)yc <= 127u) ? 1.f : 0.f;
        coff[j] = (min(max(xc, 0), 127) << 9) + go;   // x*512B + channel byte off
        roff[j] = min(max(yc, 0), 127) << 16;         // y*64KB
    }

    float q[8];
    {
        short8v qv = *(const short8v*)(q_t + (size_t)pix * C + g * 8);
        #pragma unroll
        for (int e = 0; e < 8; ++e) q[e] = bf2f((unsigned short)qv[e]) * 0.25f;  // 1/sqrt(16)
    }

    // ---- phase A: 36 per-thread partial dots (16B k loads) ----
    float d[36];
    #pragma unroll
    for (int jy = 0; jy < 6; ++jy) {
        #pragma unroll
        for (int jx = 0; jx < 6; ++jx) {
            short8v k = *(const short8v*)(kvb + (roff[jy] + coff[jx]));
            float dd = 0.f;
            #pragma unroll
            for (int e = 0; e < 8; ++e) dd += q[e] * bf2f((unsigned short)k[e]);
            d[jy * 6 + jx] = dd * (rowv[jy] * colv[jx]);
        }
    }

    // ---- scores: bilinear combine + head reduce (2 lanes/head) ----
    float s[25];
    #pragma unroll
    for (int iy = 0; iy < 5; ++iy) {
        #pragma unroll
        for (int ix = 0; ix < 5; ++ix) {
            float sp = wy0 * (wx0 * d[iy * 6 + ix]       + wx1 * d[iy * 6 + ix + 1])
                     + wy1 * (wx0 * d[(iy + 1) * 6 + ix] + wx1 * d[(iy + 1) * 6 + ix + 1]);
            sp += __shfl_xor(sp, 1);     // 2 threads = one 16-ch head
            s[iy * 5 + ix] = sp;
        }
    }

    // ---- softmax over 25 (in registers) ----
    float m = s[0];
    #pragma unroll
    for (int p = 1; p < 25; ++p) m = fmaxf(m, s[p]);
    float sum = 0.f;
    #pragma unroll
    for (int p = 0; p < 25; ++p) {
        float e = __expf(s[p] - m);
        s[p] = e;
        sum += e;
    }
    const float inv = 1.f / sum;

    // ---- corner weights: transpose bilinear of probs, fold validity ----
    float b[36];
    #pragma unroll
    for (int jy = 0; jy < 6; ++jy) {
        #pragma unroll
        for (int jx = 0; jx < 6; ++jx) {
            float acc = 0.f;
            if (jy < 5  && jx < 5)  acc += wy0 * wx0 * s[jy * 5 + jx];
            if (jy < 5  && jx >= 1) acc += wy0 * wx1 * s[jy * 5 + jx - 1];
            if (jy >= 1 && jx < 5)  acc += wy1 * wx0 * s[(jy - 1) * 5 + jx];
            if (jy >= 1 && jx >= 1) acc += wy1 * wx1 * s[(jy - 1) * 5 + jx - 1];
            b[jy * 6 + jx] = acc * (rowv[jy] * colv[jx]);
        }
    }

    // ---- phase B: 36 V gathers (16B) ----
    float oc[8] = {0.f, 0.f, 0.f, 0.f, 0.f, 0.f, 0.f, 0.f};
    #pragma unroll
    for (int jy = 0; jy < 6; ++jy) {
        #pragma unroll
        for (int jx = 0; jx < 6; ++jx) {
            short8v v = *(const short8v*)(kvb + (roff[jy] + coff[jx]) + 256);
            float bw = b[jy * 6 + jx];
            #pragma unroll
            for (int e = 0; e < 8; ++e) oc[e] += bw * bf2f((unsigned short)v[e]);
        }
    }

    short8v ob;
    #pragma unroll
    for (int e = 0; e < 8; ++e) ob[e] = (short)f2bf(oc[e] * inv);
    *(short8v*)(ao_t + (size_t)pix * C + g * 8) = ob;
}

// ---------------- kernel 4: fc + MLP + residual + stats via MFMA ----------------
// 256 blocks x 256 thr, 64 px/block (2 subtiles of 32). Pipelined staging:
// each phase issues the NEXT weight panel's loads into regs before its GEMM,
// commits to LDS after the sync. Stats -> per-block partials (no atomics).
__global__ __launch_bounds__(256, 2)
void mlp_mfma(const unsigned short* __restrict__ ao_t, const unsigned short* __restrict__ wb,
              const float* __restrict__ b1, const float* __restrict__ b2,
              float* __restrict__ out2, float2* __restrict__ partials) {
    __shared__ unsigned short wbuf[16384];    // 32 KB weight panel
    __shared__ unsigned short l1[64 * 128];   // out1 bf16 (pixel-swizzled)  16 KB
    __shared__ unsigned short lh[64 * 256];   // hid  bf16 (pixel-swizzled)  32 KB
    __shared__ float rs[8];
    const int t = threadIdx.x;
    const int p0 = blockIdx.x * 64;
    const int lane = t & 63, row16 = lane & 15, g = lane >> 4;
    const int w = t >> 6, nh = w & 1, mh = w >> 1;
    const unsigned short* wfc_b = wb + 49152;
    const unsigned short* w1_b  = wb + 65536;
    const unsigned short* w2_b  = wb + 98304;

    short8v r[8];
    stage_load(wfc_b, r, t);
    // B-fragments for GEMM1 (both subtiles) issued early too
    short8v bf[2][4];
    #pragma unroll
    for (int st = 0; st < 2; ++st) {
        int pix = p0 + st * 32 + nh * 16 + row16;
        #pragma unroll
        for (int kk = 0; kk < 4; ++kk)
            bf[st][kk] = *(const short8v*)&ao_t[(size_t)pix * 128 + kk * 32 + g * 8];
    }
    stage_write<4>(r, wbuf, t);
    __syncthreads();

    // ---- GEMM1: out1 = wfc . ao ; prefetch w1 half 0 ----
    stage_load(w1_b, r, t);
    #pragma unroll
    for (int st = 0; st < 2; ++st) {
        const int ploc = st * 32 + nh * 16 + row16;
        const int swz = (ploc & 7) << 3;
        f32x4 acc[4] = {};
        #pragma unroll
        for (int kk = 0; kk < 4; ++kk) {
            #pragma unroll
            for (int f = 0; f < 4; ++f) {
                int row = mh * 64 + f * 16 + row16;
                short8v a = *(const short8v*)&wbuf[(row << 7) + (((kk * 4 + g) ^ (row & 7)) << 3)];
                acc[f] = __builtin_amdgcn_mfma_f32_16x16x32_bf16(a, bf[st][kk], acc[f], 0, 0, 0);
            }
        }
        #pragma unroll
        for (int f = 0; f < 4; ++f)
            #pragma unroll
            for (int e = 0; e < 4; ++e) {
                int o = mh * 64 + f * 16 + g * 4 + e;
                l1[ploc * 128 + (o ^ swz)] = f2bf(acc[f][e]);
            }
    }
    __syncthreads();
    stage_write<4>(r, wbuf, t);
    __syncthreads();

    // ---- GEMM2 halves: hid = leaky(w1 . out1 + b1) ----
    #pragma unroll
    for (int s = 0; s < 2; ++s) {
        if (s == 0) stage_load(w1_b + 16384, r, t);   // prefetch w1 half 1
        else        stage_load(w2_b, r, t);           // prefetch w2 half 0
        #pragma unroll
        for (int st = 0; st < 2; ++st) {
            const int ploc = st * 32 + nh * 16 + row16;
            const int swz = (ploc & 7) << 3;
            f32x4 acc[4] = {};
            #pragma unroll
            for (int kk = 0; kk < 4; ++kk) {
                short8v b = *(const short8v*)&l1[ploc * 128 + ((kk * 32 + g * 8) ^ swz)];
                #pragma unroll
                for (int f = 0; f < 4; ++f) {
                    int row = mh * 64 + f * 16 + row16;
                    short8v a = *(const short8v*)&wbuf[(row << 7) + (((kk * 4 + g) ^ (row & 7)) << 3)];
                    acc[f] = __builtin_amdgcn_mfma_f32_16x16x32_bf16(a, b, acc[f], 0, 0, 0);
                }
            }
            #pragma unroll
            for (int f = 0; f < 4; ++f) {
                int h = s * 128 + mh * 64 + f * 16 + g * 4;
                float4 bb = *(const float4*)&b1[h];
                float hv[4] = {acc[f][0] + bb.x, acc[f][1] + bb.y,
                               acc[f][2] + bb.z, acc[f][3] + bb.w};
                #pragma unroll
                for (int e = 0; e < 4; ++e) {
                    float v = (hv[e] >= 0.f) ? hv[e] : 0.2f * hv[e];
                    lh[ploc * 256 + ((h + e) ^ swz)] = f2bf(v);
                }
            }
        }
        __syncthreads();
        if (s == 0) stage_write<4>(r, wbuf, t);
        else        stage_write<5>(r, wbuf, t);
        __syncthreads();
    }

    // ---- GEMM3 halves: out2 = w2 . hid + b2 + out1 ----
    float lsum = 0.f, lsq = 0.f;
    #pragma unroll
    for (int s = 0; s < 2; ++s) {
        if (s == 0) stage_load(w2_b + 16384, r, t);   // prefetch w2 half 1
        #pragma unroll
        for (int st = 0; st < 2; ++st) {
            const int ploc = st * 32 + nh * 16 + row16;
            const int swz = (ploc & 7) << 3;
            const int pix = p0 + ploc;
            f32x4 acc[2] = {};
            #pragma unroll
            for (int kk = 0; kk < 8; ++kk) {
                short8v b = *(const short8v*)&lh[ploc * 256 + ((kk * 32 + g * 8) ^ swz)];
                #pragma unroll
                for (int f = 0; f < 2; ++f) {
                    int row = mh * 32 + f * 16 + row16;       // local row in [0,64)
                    short8v a = *(const short8v*)&wbuf[(row << 8) + (((kk * 4 + g) ^ (row & 7)) << 3)];
                    acc[f] = __builtin_amdgcn_mfma_f32_16x16x32_bf16(a, b, acc[f], 0, 0, 0);
                }
            }
            #pragma unroll
            for (int f = 0; f < 2; ++f) {
                int ob = s * 64 + mh * 32 + f * 16 + g * 4;
                float4 b2v = *(const float4*)&b2[ob];
                ushort4 res = *(const ushort4*)&l1[ploc * 128 + (ob ^ swz)];
                float bv[4] = {b2v.x, b2v.y, b2v.z, b2v.w};
                unsigned short rr[4] = {res.x, res.y, res.z, res.w};
                #pragma unroll
                for (int e = 0; e < 4; ++e) {
                    float v = acc[f][e] + bf2f(rr[e]) + bv[e];
                    out2[(size_t)(ob + e) * HW + pix] = v;
                    lsum += v;
                    lsq += v * v;
                }
            }
        }
        if (s == 0) {
            __syncthreads();
            stage_write<5>(r, wbuf, t);
            __syncthreads();
        }
    }

    // ---- per-block stats partial (no atomics) ----
    #pragma unroll
    for (int s = 1; s < 64; s <<= 1) {
        lsum += __shfl_xor(lsum, s);
        lsq  += __shfl_xor(lsq, s);
    }
    if (lane == 0) { rs[w] = lsum; rs[4 + w] = lsq; }
    __syncthreads();
    if (t == 0)
        partials[blockIdx.x] = make_float2(rs[0] + rs[1] + rs[2] + rs[3],
                                           rs[4] + rs[5] + rs[6] + rs[7]);
}

// ---------------- kernel 5: global layernorm (in place), per-block partial reduce ----------------
__global__ void norm_kernel(float* __restrict__ out2, const float2* __restrict__ partials,
                            const float* __restrict__ gn_w, const float* __restrict__ gn_b) {
    __shared__ float rs[8];
    __shared__ float stat[2];
    const int t = threadIdx.x;

    // redundant per-block reduction of the 256 partials (2 KB, L2-hot)
    float2 p = partials[t];
    float a = p.x, bb = p.y;
    #pragma unroll
    for (int s = 1; s < 64; s <<= 1) {
        a  += __shfl_xor(a, s);
        bb += __shfl_xor(bb, s);
    }
    if ((t & 63) == 0) { rs[t >> 6] = a; rs[4 + (t >> 6)] = bb; }
    __syncthreads();
    if (t == 0) {
        const float invN = 1.f / 2097152.f;
        float mean = (rs[0] + rs[1] + rs[2] + rs[3]) * invN;
        float var = (rs[4] + rs[5] + rs[6] + rs[7]) * invN - mean * mean;
        stat[0] = mean;
        stat[1] = rsqrtf(var + 1e-5f);
    }
    __syncthreads();

    const float mean = stat[0], rstd = stat[1];
    const int gid = blockIdx.x * 256 + t;
    int base = gid * 4;
    int o = base >> 14;    // / HW
    float g = gn_w[o] * rstd;
    float b = gn_b[o];
    float4 v = *(const float4*)(out2 + base);
    float4 r;
    r.x = (v.x - mean) * g + b;
    r.y = (v.y - mean) * g + b;
    r.z = (v.z - mean) * g + b;
    r.w = (v.w - mean) * g + b;
    *(float4*)(out2 + base) = r;
}

extern "C" void kernel_launch(void* const* d_in, const int* in_sizes, int n_in,
                              void* d_out, int out_size, void* d_ws, size_t ws_size,
                              hipStream_t stream) {
    const float* query  = (const float*)d_in[0];
    const float* key    = (const float*)d_in[1];
    const float* value  = (const float*)d_in[2];
    const float* deform = (const float*)d_in[3];
    const float* w_q    = (const float*)d_in[4];
    const float* w_k    = (const float*)d_in[5];
    const float* w_v    = (const float*)d_in[6];
    const float* w_fc   = (const float*)d_in[7];
    const float* mlp_w1 = (const float*)d_in[8];
    const float* mlp_b1 = (const float*)d_in[9];
    const float* mlp_w2 = (const float*)d_in[10];
    const float* mlp_b2 = (const float*)d_in[11];
    const float* gn_w   = (const float*)d_in[12];
    const float* gn_b   = (const float*)d_in[13];

    float* out = (float*)d_out;
    char* wsb  = (char*)d_ws;

    // ws layout (bytes): q_t bf16 [0,4M) | kv_t bf16 [4M,12M) | ao bf16 [12M,16M)
    //                    | wb bf16 [16M,+256K) | partials [17M, +2K)
    unsigned short* q_t  = (unsigned short*)wsb;
    unsigned short* kv_t = (unsigned short*)(wsb + ((size_t)4 << 20));
    unsigned short* ao_t = (unsigned short*)(wsb + ((size_t)12 << 20));
    unsigned short* wb   = (unsigned short*)(wsb + ((size_t)16 << 20));
    float2* partials = (float2*)(wsb + ((size_t)17 << 20));

    prep_weights<<<512, 256, 0, stream>>>(w_q, w_k, w_v, w_fc, mlp_w1, mlp_w2, wb);
    qkv_mfma<<<512, 256, 0, stream>>>(query, key, value, wb, q_t, kv_t);
    attn_kernel<<<1024, 256, 0, stream>>>(q_t, kv_t, deform, ao_t);
    mlp_mfma<<<256, 256, 0, stream>>>(ao_t, wb, mlp_b1, mlp_b2, out, partials);
    norm_kernel<<<2048, 256, 0, stream>>>(out, partials, gn_w, gn_b);
}

// Round 12
// 49.720 us; speedup vs baseline: 13.2790x; 1.0646x over previous
//
#include <hip/hip_runtime.h>
#include <hip/hip_bf16.h>

#define HW 16384
#define W 128
#define C 128
#define HID 256

typedef __attribute__((ext_vector_type(8))) short short8v;
typedef __attribute__((ext_vector_type(4))) float f32x4;

__device__ __forceinline__ unsigned short f2bf(float f) {
    union { float f; unsigned u; } x; x.f = f;
    unsigned r = x.u + 0x7FFF + ((x.u >> 16) & 1);
    return (unsigned short)(r >> 16);
}
__device__ __forceinline__ float bf2f(unsigned short b) {
    union { unsigned u; float f; } x; x.u = ((unsigned)b) << 16;
    return x.f;
}

// ---- async-stage split: issue 32KB panel (8 x 16B per thread) into regs ----
__device__ __forceinline__ void stage_load(const unsigned short* __restrict__ src,
                                           short8v* r, int t) {
    #pragma unroll
    for (int c = 0; c < 8; ++c)
        r[c] = *(const short8v*)(src + (size_t)(c * 256 + t) * 8);
}
// ---- commit regs to LDS, XOR-swizzled: granule col ^= (row&7). RSH=log2(granules/row)
template<int RSH>
__device__ __forceinline__ void stage_write(const short8v* r, unsigned short* lds, int t) {
    #pragma unroll
    for (int c = 0; c < 8; ++c) {
        int gi = c * 256 + t;
        int row = gi >> RSH, colg = gi & ((1 << RSH) - 1);
        *(short8v*)(lds + (size_t)(((row << RSH) + (colg ^ (row & 7))) << 3)) = r[c];
    }
}
// ---- stage a 32KB bf16 panel directly from an f32 weight matrix (converting) ----
template<int RSH>
__device__ __forceinline__ void stage32f(const float* __restrict__ src,
                                         unsigned short* lds, int t) {
    #pragma unroll
    for (int c = 0; c < 8; ++c) {
        int gi = c * 256 + t;
        int row = gi >> RSH, colg = gi & ((1 << RSH) - 1);
        float4 a = *(const float4*)(src + (size_t)gi * 8);
        float4 b = *(const float4*)(src + (size_t)gi * 8 + 4);
        short8v v;
        v[0] = (short)f2bf(a.x); v[1] = (short)f2bf(a.y);
        v[2] = (short)f2bf(a.z); v[3] = (short)f2bf(a.w);
        v[4] = (short)f2bf(b.x); v[5] = (short)f2bf(b.y);
        v[6] = (short)f2bf(b.z); v[7] = (short)f2bf(b.w);
        *(short8v*)(lds + (size_t)(((row << RSH) + (colg ^ (row & 7))) << 3)) = v;
    }
}

// ---------------- kernel 1: q/k/v 1x1 convs via MFMA; also converts mlp weights ----------------
// 512 blocks x 256 thr; 32 px/block. Weight panels staged+converted from f32.
// Side job: each block converts 192 elements of {wfc,w1,w2} into wb for mlp_mfma.
__global__ __launch_bounds__(256, 2)
void qkv_mfma(const float* __restrict__ q_in, const float* __restrict__ k_in,
              const float* __restrict__ v_in,
              const float* __restrict__ w_q, const float* __restrict__ w_k,
              const float* __restrict__ w_v,
              const float* __restrict__ wfc, const float* __restrict__ w1,
              const float* __restrict__ w2,
              unsigned short* __restrict__ wb,
              unsigned short* __restrict__ q_t, unsigned short* __restrict__ kv_t) {
    __shared__ unsigned short lx[3][32 * 128];   // 24 KB inputs (pixel-swizzled)
    __shared__ unsigned short wbuf[16384];       // 32 KB weight panel
    const int t = threadIdx.x;
    const int p0 = blockIdx.x * 32;
    const int lane = t & 63, row16 = lane & 15, g = lane >> 4;
    const int w = t >> 6, nh = w & 1, mh = w >> 1;
    const int ploc = nh * 16 + row16;
    const int pix = p0 + ploc;
    const int swz = (ploc & 7) << 3;

    stage32f<4>(w_q, wbuf, t);    // wq panel, in flight during x-tile conversion

    // side job: convert mlp weights (98304 f32) spread across 512 blocks
    if (t < 192) {
        int i = blockIdx.x * 192 + t;
        float v = (i < 16384) ? wfc[i] : (i < 49152) ? w1[i - 16384] : w2[i - 49152];
        wb[i] = f2bf(v);
    }

    const float* ins[3] = {q_in, k_in, v_in};
    #pragma unroll
    for (int m = 0; m < 3; ++m) {
        #pragma unroll
        for (int it = 0; it < 16; ++it) {
            int e = t + 256 * it;          // 0..4095
            int p = e & 31, c = e >> 5;
            lx[m][p * 128 + (c ^ ((p & 7) << 3))] = f2bf(ins[m][c * HW + p0 + p]);
        }
    }

    const float* ws[3] = {w_q, w_k, w_v};
    #pragma unroll 1
    for (int m = 0; m < 3; ++m) {
        if (m > 0) {
            __syncthreads();               // previous GEMM done reading wbuf
            stage32f<4>(ws[m], wbuf, t);
        }
        __syncthreads();                   // staging (and lx on m=0) visible

        f32x4 acc[4] = {};
        #pragma unroll
        for (int kk = 0; kk < 4; ++kk) {
            short8v b = *(const short8v*)&lx[m][ploc * 128 + ((kk * 32 + g * 8) ^ swz)];
            #pragma unroll
            for (int f = 0; f < 4; ++f) {
                int row = mh * 64 + f * 16 + row16;
                short8v a = *(const short8v*)&wbuf[(row << 7) + (((kk * 4 + g) ^ (row & 7)) << 3)];
                acc[f] = __builtin_amdgcn_mfma_f32_16x16x32_bf16(a, b, acc[f], 0, 0, 0);
            }
        }
        #pragma unroll
        for (int f = 0; f < 4; ++f) {
            int o = mh * 64 + f * 16 + g * 4;
            ushort4 st;
            st.x = f2bf(acc[f][0]); st.y = f2bf(acc[f][1]);
            st.z = f2bf(acc[f][2]); st.w = f2bf(acc[f][3]);
            if (m == 0)      *(ushort4*)&q_t[(size_t)pix * 128 + o] = st;
            else if (m == 1) *(ushort4*)&kv_t[(size_t)pix * 256 + o] = st;
            else             *(ushort4*)&kv_t[(size_t)pix * 256 + 128 + o] = st;
        }
    }
}

// ---------------- kernel 2: deformable attention, factorized 6x6 corner grid ----------------
// bf16 q/kv, 16B gathers: 16 thr/px, 8 ch/thr, 16 px/block. 1024 blocks,
// linear bid->tile (dispatch-order sliding L2 window).
__global__ __launch_bounds__(256, 2)
void attn_kernel(const unsigned short* __restrict__ q_t, const unsigned short* __restrict__ kv_t,
                 const float* __restrict__ deform, unsigned short* __restrict__ ao_t) {
    const int t = threadIdx.x;
    const int pi = t >> 4;     // pixel within block (16)
    const int g = t & 15;      // channel group (8 ch = 16 B)
    const char* kvb = (const char*)kv_t;
    const int go = g * 16;

    const int jj = blockIdx.x;
    const int y = jj >> 3;
    const int x = ((jj & 7) << 4) + pi;
    const int pix = y * W + x;

    const float dx = deform[pix];
    const float dy = deform[HW + pix];
    const float fdx = floorf(dx), fdy = floorf(dy);
    const float fx = dx - fdx, fy = dy - fdy;
    const float wx0 = 1.f - fx, wx1 = fx, wy0 = 1.f - fy, wy1 = fy;
    const int x0 = x - 2 + (int)fdx;
    const int y0 = y - 2 + (int)fdy;

    int   coff[6], roff[6];
    float colv[6], rowv[6];
    #pragma unroll
    for (int j = 0; j < 6; ++j) {
        int xc = x0 + j, yc = y0 + j;
        colv[j] = ((unsigned)xc <= 127u) ? 1.f : 0.f;
        rowv[j] = ((unsigned)yc <= 127u) ? 1.f : 0.f;
        coff[j] = (min(max(xc, 0), 127) << 9) + go;   // x*512B + channel byte off
        roff[j] = min(max(yc, 0), 127) << 16;         // y*64KB
    }

    float q[8];
    {
        short8v qv = *(const short8v*)(q_t + (size_t)pix * C + g * 8);
        #pragma unroll
        for (int e = 0; e < 8; ++e) q[e] = bf2f((unsigned short)qv[e]) * 0.25f;  // 1/sqrt(16)
    }

    // ---- phase A: 36 per-thread partial dots (16B k loads) ----
    float d[36];
    #pragma unroll
    for (int jy = 0; jy < 6; ++jy) {
        #pragma unroll
        for (int jx = 0; jx < 6; ++jx) {
            short8v k = *(const short8v*)(kvb + (roff[jy] + coff[jx]));
            float dd = 0.f;
            #pragma unroll
            for (int e = 0; e < 8; ++e) dd += q[e] * bf2f((unsigned short)k[e]);
            d[jy * 6 + jx] = dd * (rowv[jy] * colv[jx]);
        }
    }

    // ---- scores: bilinear combine + head reduce (2 lanes/head) ----
    float s[25];
    #pragma unroll
    for (int iy = 0; iy < 5; ++iy) {
        #pragma unroll
        for (int ix = 0; ix < 5; ++ix) {
            float sp = wy0 * (wx0 * d[iy * 6 + ix]       + wx1 * d[iy * 6 + ix + 1])
                     + wy1 * (wx0 * d[(iy + 1) * 6 + ix] + wx1 * d[(iy + 1) * 6 + ix + 1]);
            sp += __shfl_xor(sp, 1);     // 2 threads = one 16-ch head
            s[iy * 5 + ix] = sp;
        }
    }

    // ---- softmax over 25 (in registers) ----
    float m = s[0];
    #pragma unroll
    for (int p = 1; p < 25; ++p) m = fmaxf(m, s[p]);
    float sum = 0.f;
    #pragma unroll
    for (int p = 0; p < 25; ++p) {
        float e = __expf(s[p] - m);
        s[p] = e;
        sum += e;
    }
    const float inv = 1.f / sum;

    // ---- corner weights: transpose bilinear of probs, fold validity ----
    float b[36];
    #pragma unroll
    for (int jy = 0; jy < 6; ++jy) {
        #pragma unroll
        for (int jx = 0; jx < 6; ++jx) {
            float acc = 0.f;
            if (jy < 5  && jx < 5)  acc += wy0 * wx0 * s[jy * 5 + jx];
            if (jy < 5  && jx >= 1) acc += wy0 * wx1 * s[jy * 5 + jx - 1];
            if (jy >= 1 && jx < 5)  acc += wy1 * wx0 * s[(jy - 1) * 5 + jx];
            if (jy >= 1 && jx >= 1) acc += wy1 * wx1 * s[(jy - 1) * 5 + jx - 1];
            b[jy * 6 + jx] = acc * (rowv[jy] * colv[jx]);
        }
    }

    // ---- phase B: 36 V gathers (16B) ----
    float oc[8] = {0.f, 0.f, 0.f, 0.f, 0.f, 0.f, 0.f, 0.f};
    #pragma unroll
    for (int jy = 0; jy < 6; ++jy) {
        #pragma unroll
        for (int jx = 0; jx < 6; ++jx) {
            short8v v = *(const short8v*)(kvb + (roff[jy] + coff[jx]) + 256);
            float bw = b[jy * 6 + jx];
            #pragma unroll
            for (int e = 0; e < 8; ++e) oc[e] += bw * bf2f((unsigned short)v[e]);
        }
    }

    short8v ob;
    #pragma unroll
    for (int e = 0; e < 8; ++e) ob[e] = (short)f2bf(oc[e] * inv);
    *(short8v*)(ao_t + (size_t)pix * C + g * 8) = ob;
}

// ---------------- kernel 3: fc + MLP + residual + stats via MFMA ----------------
// 512 blocks x 256 thr, 32 px/block; 56KB LDS -> 2 blocks/CU so one block's
// staging hides under the other's MFMA. Pipelined weight staging as before.
__global__ __launch_bounds__(256, 2)
void mlp_mfma(const unsigned short* __restrict__ ao_t, const unsigned short* __restrict__ wb,
              const float* __restrict__ b1, const float* __restrict__ b2,
              float* __restrict__ out2, float2* __restrict__ partials) {
    __shared__ unsigned short wbuf[16384];    // 32 KB weight panel
    __shared__ unsigned short l1[32 * 128];   // out1 bf16 (pixel-swizzled)   8 KB
    __shared__ unsigned short lh[32 * 256];   // hid  bf16 (pixel-swizzled)  16 KB
    __shared__ float rs[8];
    const int t = threadIdx.x;
    const int p0 = blockIdx.x * 32;
    const int lane = t & 63, row16 = lane & 15, g = lane >> 4;
    const int w = t >> 6, nh = w & 1, mh = w >> 1;
    const int ploc = nh * 16 + row16;
    const int pix = p0 + ploc;
    const int swz = (ploc & 7) << 3;
    const unsigned short* wfc_b = wb;
    const unsigned short* w1_b  = wb + 16384;
    const unsigned short* w2_b  = wb + 49152;

    short8v r[8];
    stage_load(wfc_b, r, t);
    // B-fragments for GEMM1 issued early too
    short8v bf[4];
    #pragma unroll
    for (int kk = 0; kk < 4; ++kk)
        bf[kk] = *(const short8v*)&ao_t[(size_t)pix * 128 + kk * 32 + g * 8];
    stage_write<4>(r, wbuf, t);
    __syncthreads();

    // ---- GEMM1: out1 = wfc . ao ; prefetch w1 half 0 ----
    stage_load(w1_b, r, t);
    {
        f32x4 acc[4] = {};
        #pragma unroll
        for (int kk = 0; kk < 4; ++kk) {
            #pragma unroll
            for (int f = 0; f < 4; ++f) {
                int row = mh * 64 + f * 16 + row16;
                short8v a = *(const short8v*)&wbuf[(row << 7) + (((kk * 4 + g) ^ (row & 7)) << 3)];
                acc[f] = __builtin_amdgcn_mfma_f32_16x16x32_bf16(a, bf[kk], acc[f], 0, 0, 0);
            }
        }
        #pragma unroll
        for (int f = 0; f < 4; ++f)
            #pragma unroll
            for (int e = 0; e < 4; ++e) {
                int o = mh * 64 + f * 16 + g * 4 + e;
                l1[ploc * 128 + (o ^ swz)] = f2bf(acc[f][e]);
            }
    }
    __syncthreads();
    stage_write<4>(r, wbuf, t);
    __syncthreads();

    // ---- GEMM2 halves: hid = leaky(w1 . out1 + b1) ----
    #pragma unroll
    for (int s = 0; s < 2; ++s) {
        if (s == 0) stage_load(w1_b + 16384, r, t);   // prefetch w1 half 1
        else        stage_load(w2_b, r, t);           // prefetch w2 half 0
        f32x4 acc[4] = {};
        #pragma unroll
        for (int kk = 0; kk < 4; ++kk) {
            short8v b = *(const short8v*)&l1[ploc * 128 + ((kk * 32 + g * 8) ^ swz)];
            #pragma unroll
            for (int f = 0; f < 4; ++f) {
                int row = mh * 64 + f * 16 + row16;
                short8v a = *(const short8v*)&wbuf[(row << 7) + (((kk * 4 + g) ^ (row & 7)) << 3)];
                acc[f] = __builtin_amdgcn_mfma_f32_16x16x32_bf16(a, b, acc[f], 0, 0, 0);
            }
        }
        #pragma unroll
        for (int f = 0; f < 4; ++f) {
            int h = s * 128 + mh * 64 + f * 16 + g * 4;
            float4 bb = *(const float4*)&b1[h];
            float hv[4] = {acc[f][0] + bb.x, acc[f][1] + bb.y,
                           acc[f][2] + bb.z, acc[f][3] + bb.w};
            #pragma unroll
            for (int e = 0; e < 4; ++e) {
                float v = (hv[e] >= 0.f) ? hv[e] : 0.2f * hv[e];
                lh[ploc * 256 + ((h + e) ^ swz)] = f2bf(v);
            }
        }
        __syncthreads();
        if (s == 0) stage_write<4>(r, wbuf, t);
        else        stage_write<5>(r, wbuf, t);
        __syncthreads();
    }

    // ---- GEMM3 halves: out2 = w2 . hid + b2 + out1 ----
    float lsum = 0.f, lsq = 0.f;
    #pragma unroll
    for (int s = 0; s < 2; ++s) {
        if (s == 0) stage_load(w2_b + 16384, r, t);   // prefetch w2 half 1
        f32x4 acc[2] = {};
        #pragma unroll
        for (int kk = 0; kk < 8; ++kk) {
            short8v b = *(const short8v*)&lh[ploc * 256 + ((kk * 32 + g * 8) ^ swz)];
            #pragma unroll
            for (int f = 0; f < 2; ++f) {
                int row = mh * 32 + f * 16 + row16;       // local row in [0,64)
                short8v a = *(const short8v*)&wbuf[(row << 8) + (((kk * 4 + g) ^ (row & 7)) << 3)];
                acc[f] = __builtin_amdgcn_mfma_f32_16x16x32_bf16(a, b, acc[f], 0, 0, 0);
            }
        }
        #pragma unroll
        for (int f = 0; f < 2; ++f) {
            int ob = s * 64 + mh * 32 + f * 16 + g * 4;
            float4 b2v = *(const float4*)&b2[ob];
            ushort4 res = *(const ushort4*)&l1[ploc * 128 + (ob ^ swz)];
            float bv[4] = {b2v.x, b2v.y, b2v.z, b2v.w};
            unsigned short rr[4] = {res.x, res.y, res.z, res.w};
            #pragma unroll
            for (int e = 0; e < 4; ++e) {
                float v = acc[f][e] + bf2f(rr[e]) + bv[e];
                out2[(size_t)(ob + e) * HW + pix] = v;
                lsum += v;
                lsq += v * v;
            }
        }
        if (s == 0) {
            __syncthreads();
            stage_write<5>(r, wbuf, t);
            __syncthreads();
        }
    }

    // ---- per-block stats partial (no atomics) ----
    #pragma unroll
    for (int s = 1; s < 64; s <<= 1) {
        lsum += __shfl_xor(lsum, s);
        lsq  += __shfl_xor(lsq, s);
    }
    if (lane == 0) { rs[w] = lsum; rs[4 + w] = lsq; }
    __syncthreads();
    if (t == 0)
        partials[blockIdx.x] = make_float2(rs[0] + rs[1] + rs[2] + rs[3],
                                           rs[4] + rs[5] + rs[6] + rs[7]);
}

// ---------------- kernel 4: global layernorm (in place), per-block partial reduce ----------------
__global__ void norm_kernel(float* __restrict__ out2, const float2* __restrict__ partials,
                            const float* __restrict__ gn_w, const float* __restrict__ gn_b) {
    __shared__ float rs[8];
    __shared__ float stat[2];
    const int t = threadIdx.x;

    // redundant per-block reduction of the 512 partials (4 KB, L2-hot)
    float2 p0 = partials[t];
    float2 p1 = partials[t + 256];
    float a = p0.x + p1.x, bb = p0.y + p1.y;
    #pragma unroll
    for (int s = 1; s < 64; s <<= 1) {
        a  += __shfl_xor(a, s);
        bb += __shfl_xor(bb, s);
    }
    if ((t & 63) == 0) { rs[t >> 6] = a; rs[4 + (t >> 6)] = bb; }
    __syncthreads();
    if (t == 0) {
        const float invN = 1.f / 2097152.f;
        float mean = (rs[0] + rs[1] + rs[2] + rs[3]) * invN;
        float var = (rs[4] + rs[5] + rs[6] + rs[7]) * invN - mean * mean;
        stat[0] = mean;
        stat[1] = rsqrtf(var + 1e-5f);
    }
    __syncthreads();

    const float mean = stat[0], rstd = stat[1];
    const int gid = blockIdx.x * 256 + t;
    int base = gid * 4;
    int o = base >> 14;    // / HW
    float g = gn_w[o] * rstd;
    float b = gn_b[o];
    float4 v = *(const float4*)(out2 + base);
    float4 r;
    r.x = (v.x - mean) * g + b;
    r.y = (v.y - mean) * g + b;
    r.z = (v.z - mean) * g + b;
    r.w = (v.w - mean) * g + b;
    *(float4*)(out2 + base) = r;
}

extern "C" void kernel_launch(void* const* d_in, const int* in_sizes, int n_in,
                              void* d_out, int out_size, void* d_ws, size_t ws_size,
                              hipStream_t stream) {
    const float* query  = (const float*)d_in[0];
    const float* key    = (const float*)d_in[1];
    const float* value  = (const float*)d_in[2];
    const float* deform = (const float*)d_in[3];
    const float* w_q    = (const float*)d_in[4];
    const float* w_k    = (const float*)d_in[5];
    const float* w_v    = (const float*)d_in[6];
    const float* w_fc   = (const float*)d_in[7];
    const float* mlp_w1 = (const float*)d_in[8];
    const float* mlp_b1 = (const float*)d_in[9];
    const float* mlp_w2 = (const float*)d_in[10];
    const float* mlp_b2 = (const float*)d_in[11];
    const float* gn_w   = (const float*)d_in[12];
    const float* gn_b   = (const float*)d_in[13];

    float* out = (float*)d_out;
    char* wsb  = (char*)d_ws;

    // ws layout (bytes): q_t bf16 [0,4M) | kv_t bf16 [4M,12M) | ao bf16 [12M,16M)
    //                    | wb bf16 [16M,+192K) | partials [17M, +4K)
    unsigned short* q_t  = (unsigned short*)wsb;
    unsigned short* kv_t = (unsigned short*)(wsb + ((size_t)4 << 20));
    unsigned short* ao_t = (unsigned short*)(wsb + ((size_t)12 << 20));
    unsigned short* wb   = (unsigned short*)(wsb + ((size_t)16 << 20));
    float2* partials = (float2*)(wsb + ((size_t)17 << 20));

    qkv_mfma<<<512, 256, 0, stream>>>(query, key, value, w_q, w_k, w_v,
                                      w_fc, mlp_w1, mlp_w2, wb, q_t, kv_t);
    attn_kernel<<<1024, 256, 0, stream>>>(q_t, kv_t, deform, ao_t);
    mlp_mfma<<<512, 256, 0, stream>>>(ao_t, wb, mlp_b1, mlp_b2, out, partials);
    norm_kernel<<<2048, 256, 0, stream>>>(out, partials, gn_w, gn_b);
}